// Round 9
// baseline (1305.741 us; speedup 1.0000x reference)
//
#include <hip/hip_runtime.h>
#include <hip/hip_bf16.h>
#include <math.h>

typedef __hip_bfloat16 bf16;
typedef __attribute__((ext_vector_type(8))) short short8;   // 8 bf16 (4 VGPRs)
typedef __attribute__((ext_vector_type(4))) float f32x4;

constexpr int B_ = 8, S_ = 1024, F_ = 8, D_ = 512, H_ = 8, E_ = 4;
constexpr int T_  = B_ * S_;       // 8192 tokens
constexpr int D3_ = 3 * D_;        // 1536
constexpr int CAP_ = T_ * 2 + E_ * 128;   // sparse row capacity (top-2, 128-pad/expert)

__device__ __forceinline__ float b2f(bf16 v) { return __bfloat162float(v); }
__device__ __forceinline__ float ldin(const void* p, size_t i, int bf) {
  return bf ? __bfloat162float(((const bf16*)p)[i]) : ((const float*)p)[i];
}
__device__ __forceinline__ void gload16(const void* g, void* l) {
  __builtin_amdgcn_global_load_lds((const __attribute__((address_space(1))) unsigned int*)g,
                                   (__attribute__((address_space(3))) unsigned int*)l, 16, 0, 0);
}

// ---------------- dtype detector ----------------
__global__ void detect_kernel(const void* __restrict__ x, int* __restrict__ flag) {
  if (threadIdx.x == 0 && blockIdx.x == 0) {
    const unsigned short* u = (const unsigned short*)x;
    int c = 0;
    for (int i = 0; i < 256; i += 2) {
      int ex = (u[i] >> 7) & 0xFF;
      if (ex >= 96 && ex <= 144) c++;
    }
    flag[0] = (c >= 64) ? 1 : 0;
  }
}

// ---------------- instance norm over time axis ----------------
__global__ __launch_bounds__(256) void instnorm_kernel(const void* __restrict__ x,
                                                       float* __restrict__ xn,
                                                       const int* __restrict__ flag) {
  const int bf = flag[0];
  int b = blockIdx.x / F_, f = blockIdx.x % F_;
  int tid = threadIdx.x;
  __shared__ float red[256];
  const int base = b * S_ * F_ + f;
  float s = 0.f;
  for (int j = tid; j < S_; j += 256) s += ldin(x, base + j * F_, bf);
  red[tid] = s; __syncthreads();
  for (int w = 128; w; w >>= 1) { if (tid < w) red[tid] += red[tid + w]; __syncthreads(); }
  float mean = red[0] / S_;
  __syncthreads();
  float v = 0.f;
  for (int j = tid; j < S_; j += 256) { float d = ldin(x, base + j * F_, bf) - mean; v += d * d; }
  red[tid] = v; __syncthreads();
  for (int w = 128; w; w >>= 1) { if (tid < w) red[tid] += red[tid + w]; __syncthreads(); }
  float inv = 1.f / (sqrtf(red[0] / (float)(S_ - 1)) + 1e-5f);
  for (int j = tid; j < S_; j += 256) xn[base + j * F_] = (ldin(x, base + j * F_, bf) - mean) * inv;
}

// ---------------- input projection + freq emb + positional encoding ----------------
__global__ __launch_bounds__(256) void input_proj_kernel(const float* __restrict__ xn,
                                                         const void* __restrict__ Wp,
                                                         const void* __restrict__ bp,
                                                         const void* __restrict__ femb,
                                                         const int* __restrict__ freq_idx,
                                                         float* __restrict__ h,
                                                         bf16* __restrict__ hb16,
                                                         const int* __restrict__ flag) {
  const int bf = flag[0];
  int idx = blockIdx.x * 256 + threadIdx.x;
  int d = idx % D_;
  int t = idx / D_;
  int s = t % S_;
  int fi = freq_idx[0];
  float acc = ldin(bp, d, bf) + ldin(femb, (size_t)fi * D_ + d, bf);
  int i2 = d & ~1;
  const float cexp = -9.2103403719761836f / (float)D_;
  float ang = (float)s * expf((float)i2 * cexp);
  acc += (d & 1) ? cosf(ang) : sinf(ang);
  const float* xr = xn + t * F_;
#pragma unroll
  for (int f = 0; f < F_; f++) acc += xr[f] * ldin(Wp, (size_t)d * F_ + f, bf);
  h[idx] = acc;
  hb16[idx] = __float2bfloat16(acc);
}

// ---------------- dense MFMA GEMM, BK=64, XCD-clustered swizzle ----------------
// MODE 3: C bf16 = acc + bias  (QKV). MODE 0: partial bf16 slice per z (O-proj).
template <int MODE>
__global__ __launch_bounds__(256, 3) void mfma_gemm(
    const bf16* __restrict__ A, const void* __restrict__ Wt, size_t woff,
    const void* __restrict__ bias, size_t boff, void* __restrict__ C_,
    int Kd, int lda, int ldb, int ldc, const int* __restrict__ flag) {
  const int wbf = flag[0];
  __shared__ bf16 As[128][64];
  __shared__ bf16 Bs[128][64];
  const int tid = threadIdx.x;
  const int ln = tid & 63, wv = tid >> 6;
  // XCD-clustering swizzle: hw xcd = linear_id % 8; give each xcd a contiguous tile range
  int id = blockIdx.x + gridDim.x * blockIdx.y;
  int nb8 = (gridDim.x * gridDim.y) >> 3;
  int g = (id & 7) * nb8 + (id >> 3);
  const int n0 = (g % gridDim.x) * 128;
  const int m0 = (g / gridDim.x) * 128;
  const int wr = (wv >> 1) * 64, wc = (wv & 1) * 64;
  const int mrow = ln & 15, quad = ln >> 4;
  const int sr8 = ln >> 3;           // staging row-in-8 group
  const int sk8 = (ln & 7) * 8;      // staging k offset (elements)
  const int kchunk = Kd / gridDim.z;
  const int kbeg = blockIdx.z * kchunk;

  f32x4 acc[4][4];
#pragma unroll
  for (int i = 0; i < 4; i++)
#pragma unroll
    for (int j = 0; j < 4; j++) acc[i][j] = (f32x4){0.f, 0.f, 0.f, 0.f};

  for (int k0 = kbeg; k0 < kbeg + kchunk; k0 += 64) {
#pragma unroll
    for (int j = 0; j < 4; j++) {
      int row = (4 * j + wv) * 8 + sr8;
      gload16(A + (size_t)(m0 + row) * lda + k0 + sk8,
              (char*)&As[0][0] + (size_t)(4 * j + wv) * 1024);
    }
#pragma unroll
    for (int j = 0; j < 4; j++) {
      int row = (4 * j + wv) * 8 + sr8;
      size_t baddr = woff + (size_t)(n0 + row) * ldb + k0 + sk8;
      if (wbf) {
        gload16((const bf16*)Wt + baddr, (char*)&Bs[0][0] + (size_t)(4 * j + wv) * 1024);
      } else {
        const float* gp = (const float*)Wt + baddr;
        short8 v;
#pragma unroll
        for (int u = 0; u < 8; u++) { bf16 t = __float2bfloat16(gp[u]); v[u] = *(short*)&t; }
        *(short8*)&Bs[row][sk8] = v;
      }
    }
    __syncthreads();
#pragma unroll
    for (int ks = 0; ks < 2; ks++) {
      short8 af[4], bfr[4];
#pragma unroll
      for (int t = 0; t < 4; t++) {
        af[t]  = *(const short8*)&As[wr + t * 16 + mrow][quad * 8 + ks * 32];
        bfr[t] = *(const short8*)&Bs[wc + t * 16 + mrow][quad * 8 + ks * 32];
      }
#pragma unroll
      for (int i = 0; i < 4; i++)
#pragma unroll
        for (int j = 0; j < 4; j++)
          acc[i][j] = __builtin_amdgcn_mfma_f32_16x16x32_bf16(af[i], bfr[j], acc[i][j], 0, 0, 0);
    }
    __syncthreads();
  }

  bf16* slice = (MODE == 0) ? (bf16*)C_ + (size_t)blockIdx.z * T_ * D_ : (bf16*)C_;
#pragma unroll
  for (int tj = 0; tj < 4; tj++) {
    int n = n0 + wc + tj * 16 + mrow;
    float bv = (MODE == 3) ? ldin(bias, boff + n, wbf) : 0.f;
#pragma unroll
    for (int ti = 0; ti < 4; ti++) {
      int mbase = m0 + wr + ti * 16 + quad * 4;
#pragma unroll
      for (int r = 0; r < 4; r++) {
        int m = mbase + r;
        float v = acc[ti][tj][r];
        slice[(size_t)m * ldc + n] = __float2bfloat16(MODE == 3 ? v + bv : v);
      }
    }
  }
}

// ---------------- MFMA flash attention: 128-query tile, swizzled V transpose --------
__global__ __launch_bounds__(256) void attn_kernel(const bf16* __restrict__ qkv,
                                                   bf16* __restrict__ o) {
  __shared__ bf16 Qs[128][72];
  __shared__ bf16 Ks[64][72];
  __shared__ bf16 Vt[64][72];    // [d][k ^ swz(d)]
  __shared__ bf16 Ps[128][72];   // [q][k]
  const int tid = threadIdx.x;
  const int ln = tid & 63, wv = tid >> 6;
  const int mrow = ln & 15, quad = ln >> 4;
  const int qt = blockIdx.x & 7, hh = (blockIdx.x >> 3) & 7, b = blockIdx.x >> 6;
  const int q0 = qt * 128;
  const int sr = tid >> 2;          // staging row 0..63
  const int sg = tid & 3;           // staging col group
  const int sc = sg * 8;            // staging col base; chunks at sc, sc+32

  // stage Q (128 rows, two passes)
#pragma unroll
  for (int p = 0; p < 2; p++) {
    int row = sr + p * 64;
    const bf16* src = qkv + (size_t)(b * S_ + q0 + row) * D3_ + hh * 64;
    *(short8*)&Qs[row][sc]      = *(const short8*)(src + sc);
    *(short8*)&Qs[row][sc + 32] = *(const short8*)(src + sc + 32);
  }
  __syncthreads();
  short8 aq[2][2];
#pragma unroll
  for (int g = 0; g < 2; g++) {
    aq[g][0] = *(const short8*)&Qs[wv * 32 + g * 16 + mrow][quad * 8];
    aq[g][1] = *(const short8*)&Qs[wv * 32 + g * 16 + mrow][quad * 8 + 32];
  }

  float m_st[2][4], l_st[2][4];
  f32x4 oacc[2][4];
#pragma unroll
  for (int g = 0; g < 2; g++)
#pragma unroll
    for (int t = 0; t < 4; t++) {
      m_st[g][t] = -1e30f; l_st[g][t] = 0.f;
      oacc[g][t] = (f32x4){0.f, 0.f, 0.f, 0.f};
    }

  for (int kt = 0; kt < 16; kt++) {
    int k0 = kt * 64;
    __syncthreads();
    // stage K: Ks[k][d]
    {
      const bf16* src = qkv + (size_t)(b * S_ + k0 + sr) * D3_ + D_ + hh * 64;
      *(short8*)&Ks[sr][sc]      = *(const short8*)(src + sc);
      *(short8*)&Ks[sr][sc + 32] = *(const short8*)(src + sc + 32);
    }
    // stage V transposed with XOR swizzle: Vt[d][k ^ ((d>>3)&3)*16]
    {
      const bf16* src = qkv + (size_t)(b * S_ + k0 + sr) * D3_ + 2 * D_ + hh * 64;
      short8 v0 = *(const short8*)(src + sc);
      short8 v1 = *(const short8*)(src + sc + 32);
      int col0 = sr ^ (sg << 4);
      int col1 = sr ^ (((sg + 4) & 3) << 4);
#pragma unroll
      for (int u = 0; u < 8; u++) {
        *(short*)&Vt[sc + u][col0]      = v0[u];
        *(short*)&Vt[sc + 32 + u][col1] = v1[u];
      }
    }
    __syncthreads();
    // S tiles: 32 q-rows per wave x 64 keys
    f32x4 s[2][4];
#pragma unroll
    for (int g = 0; g < 2; g++)
#pragma unroll
      for (int t = 0; t < 4; t++) {
        s[g][t] = (f32x4){0.f, 0.f, 0.f, 0.f};
#pragma unroll
        for (int ks = 0; ks < 2; ks++) {
          short8 bk = *(const short8*)&Ks[t * 16 + mrow][quad * 8 + ks * 32];
          s[g][t] = __builtin_amdgcn_mfma_f32_16x16x32_bf16(aq[g][ks], bk, s[g][t], 0, 0, 0);
        }
      }
    // online softmax (row q = wv*32 + g*16 + quad*4 + r; 16 lanes share a row)
#pragma unroll
    for (int g = 0; g < 2; g++)
#pragma unroll
      for (int r = 0; r < 4; r++) {
        float rm = fmaxf(fmaxf(s[g][0][r], s[g][1][r]), fmaxf(s[g][2][r], s[g][3][r])) * 0.125f;
#pragma unroll
        for (int off = 8; off; off >>= 1) rm = fmaxf(rm, __shfl_xor(rm, off, 64));
        float mnew = fmaxf(m_st[g][r], rm);
        float alpha = __expf(m_st[g][r] - mnew);
        m_st[g][r] = mnew;
        float rs = 0.f;
#pragma unroll
        for (int t = 0; t < 4; t++) {
          float p = __expf(s[g][t][r] * 0.125f - mnew);
          rs += p;
          Ps[wv * 32 + g * 16 + quad * 4 + r][t * 16 + mrow] = __float2bfloat16(p);
        }
#pragma unroll
        for (int off = 8; off; off >>= 1) rs += __shfl_xor(rs, off, 64);
        l_st[g][r] = l_st[g][r] * alpha + rs;
#pragma unroll
        for (int t = 0; t < 4; t++) oacc[g][t][r] *= alpha;
      }
    // PV (Ps rows written by this wave == rows it reads; no barrier needed)
#pragma unroll
    for (int g = 0; g < 2; g++) {
      short8 ap[2];
      ap[0] = *(const short8*)&Ps[wv * 32 + g * 16 + mrow][quad * 8];
      ap[1] = *(const short8*)&Ps[wv * 32 + g * 16 + mrow][quad * 8 + 32];
#pragma unroll
      for (int t = 0; t < 4; t++) {
        int d = t * 16 + mrow;
        int swz = ((d >> 3) & 3) << 4;
#pragma unroll
        for (int ks = 0; ks < 2; ks++) {
          short8 bv = *(const short8*)&Vt[d][(quad * 8 + ks * 32) ^ swz];
          oacc[g][t] = __builtin_amdgcn_mfma_f32_16x16x32_bf16(ap[ks], bv, oacc[g][t], 0, 0, 0);
        }
      }
    }
  }
  // epilogue
#pragma unroll
  for (int g = 0; g < 2; g++)
#pragma unroll
    for (int r = 0; r < 4; r++) {
      float inv = 1.f / l_st[g][r];
      size_t base = (size_t)(b * S_ + q0 + wv * 32 + g * 16 + quad * 4 + r) * D_ + hh * 64;
#pragma unroll
      for (int t = 0; t < 4; t++)
        o[base + t * 16 + mrow] = __float2bfloat16(oacc[g][t][r] * inv);
    }
}

// ---------------- fused: sum partial slices + bias + residual + LayerNorm ----------
__global__ __launch_bounds__(256) void reduce_ln_kernel(float* __restrict__ h,
                                                        bf16* __restrict__ hb16,
                                                        const bf16* __restrict__ ps,
                                                        int nsl, int mode,
                                                        const void* __restrict__ bias,
                                                        size_t boff,
                                                        const float* __restrict__ cw,
                                                        const void* __restrict__ eb2p,
                                                        size_t e2off,
                                                        const void* __restrict__ g,
                                                        const void* __restrict__ beta,
                                                        size_t off,
                                                        const int* __restrict__ flag) {
  const int bf = flag[0];
  int t = blockIdx.x, tid = threadIdx.x;
  __shared__ float r1[256], r2[256];
  const size_t base = (size_t)t * D_;
  float o0 = 0.f, o1 = 0.f;
  for (int s = 0; s < nsl; s++) {
    o0 += b2f(ps[(size_t)s * T_ * D_ + base + tid]);
    o1 += b2f(ps[(size_t)s * T_ * D_ + base + tid + 256]);
  }
  if (mode == 0) {
    o0 += ldin(bias, boff + tid, bf);
    o1 += ldin(bias, boff + tid + 256, bf);
  } else {
#pragma unroll
    for (int e = 0; e < 4; e++) {
      float w = cw[t * 4 + e];
      o0 += w * ldin(eb2p, e2off + e * D_ + tid, bf);
      o1 += w * ldin(eb2p, e2off + e * D_ + tid + 256, bf);
    }
  }
  float* hr = h + base;
  float v0 = hr[tid] + o0;
  float v1 = hr[tid + 256] + o1;
  r1[tid] = v0 + v1;
  r2[tid] = v0 * v0 + v1 * v1;
  __syncthreads();
  for (int w = 128; w; w >>= 1) { if (tid < w) { r1[tid] += r1[tid + w]; r2[tid] += r2[tid + w]; } __syncthreads(); }
  float mean = r1[0] * (1.f / D_);
  float var  = r2[0] * (1.f / D_) - mean * mean;
  float rstd = rsqrtf(var + 1e-5f);
  float n0 = (v0 - mean) * rstd * ldin(g, off + tid, bf) + ldin(beta, off + tid, bf);
  float n1 = (v1 - mean) * rstd * ldin(g, off + tid + 256, bf) + ldin(beta, off + tid + 256, bf);
  hr[tid] = n0;
  hr[tid + 256] = n1;
  hb16[base + tid] = __float2bfloat16(n0);
  hb16[base + tid + 256] = __float2bfloat16(n1);
}

// ---------------- MoE gating: softmax over E=4, top-2; emits routing info ----------
__global__ __launch_bounds__(256) void gate_kernel(const float* __restrict__ hbuf,
                                                   const void* __restrict__ gw, size_t gwoff,
                                                   const void* __restrict__ gb, size_t gboff,
                                                   float* __restrict__ cw,
                                                   int* __restrict__ einfo,
                                                   float* __restrict__ w0a,
                                                   float* __restrict__ w1a,
                                                   const int* __restrict__ flag) {
  const int bf = flag[0];
  int lane = threadIdx.x & 63, wv = threadIdx.x >> 6;
  int t = blockIdx.x * 4 + wv;
  const float* xr = hbuf + (size_t)t * D_;
  float a[4] = {0, 0, 0, 0};
  for (int d = lane; d < D_; d += 64) {
    float xv = xr[d];
#pragma unroll
    for (int e = 0; e < 4; e++) a[e] += xv * ldin(gw, gwoff + e * D_ + d, bf);
  }
#pragma unroll
  for (int e = 0; e < 4; e++)
    for (int off = 32; off; off >>= 1) a[e] += __shfl_xor(a[e], off, 64);
  if (lane == 0) {
    float lg[4];
#pragma unroll
    for (int e = 0; e < 4; e++) lg[e] = a[e] + ldin(gb, gboff + e, bf);
    float m = fmaxf(fmaxf(lg[0], lg[1]), fmaxf(lg[2], lg[3]));
    float p[4], s = 0.f;
#pragma unroll
    for (int e = 0; e < 4; e++) { p[e] = __expf(lg[e] - m); s += p[e]; }
#pragma unroll
    for (int e = 0; e < 4; e++) p[e] /= s;
    int i0 = 0;
    for (int e = 1; e < 4; e++) if (p[e] > p[i0]) i0 = e;
    int i1 = -1;
    for (int e = 0; e < 4; e++) if (e != i0 && (i1 < 0 || p[e] > p[i1])) i1 = e;
    float s2 = p[i0] + p[i1];
    float ww0 = p[i0] / s2, ww1 = p[i1] / s2;
    float outw[4] = {0, 0, 0, 0};
    outw[i0] = ww0; outw[i1] = ww1;
#pragma unroll
    for (int e = 0; e < 4; e++) cw[t * 4 + e] = outw[e];
    einfo[t] = i0 | (i1 << 4);
    w0a[t] = ww0; w1a[t] = ww1;
  }
}

// ---------------- route scan: counts -> 128-aligned offsets (1 block) ----------------
__global__ __launch_bounds__(256) void route_scan_kernel(const int* __restrict__ einfo,
                                                         int* __restrict__ off,
                                                         int* __restrict__ endp,
                                                         int* __restrict__ cur) {
  __shared__ int red[4][256];
  int tid = threadIdx.x;
  int c[4] = {0, 0, 0, 0};
  for (int t = tid; t < T_; t += 256) {
    int inf = einfo[t];
    c[inf & 15]++;
    c[(inf >> 4) & 15]++;
  }
#pragma unroll
  for (int e = 0; e < 4; e++) red[e][tid] = c[e];
  __syncthreads();
  for (int w = 128; w; w >>= 1) {
    if (tid < w)
#pragma unroll
      for (int e = 0; e < 4; e++) red[e][tid] += red[e][tid + w];
    __syncthreads();
  }
  if (tid == 0) {
    int o = 0;
#pragma unroll
    for (int e = 0; e < 4; e++) {
      int cnt = red[e][0];
      off[e] = o;
      endp[e] = o + cnt;
      cur[e] = 0;
      o += ((cnt + 127) / 128) * 128;
    }
  }
}

// ---------------- scatter: token -> (expert bucket, rank), ballot-aggregated --------
__global__ __launch_bounds__(256) void scatter_kernel(const int* __restrict__ einfo,
                                                      const float* __restrict__ w0a,
                                                      const float* __restrict__ w1a,
                                                      const int* __restrict__ off,
                                                      int* __restrict__ cur,
                                                      int* __restrict__ pack,
                                                      float* __restrict__ wlist) {
  int t = blockIdx.x * 256 + threadIdx.x;
  int lane = threadIdx.x & 63;
  int inf = einfo[t];
#pragma unroll
  for (int rank = 0; rank < 2; rank++) {
    int my_e = (rank == 0) ? (inf & 15) : ((inf >> 4) & 15);
    float w = (rank == 0) ? w0a[t] : w1a[t];
#pragma unroll
    for (int e = 0; e < 4; e++) {
      bool p = (my_e == e);
      unsigned long long mask = __ballot(p);
      if (!mask) continue;
      int leader = __ffsll((long long)mask) - 1;
      int base = 0;
      if (lane == leader) base = atomicAdd(&cur[e], (int)__popcll(mask));
      base = __shfl(base, leader, 64);
      if (p) {
        int pos = off[e] + base + (int)__popcll(mask & ((1ULL << lane) - 1ULL));
        pack[pos] = t * 2 + rank;
        wlist[pos] = w;
      }
    }
  }
}

// ---------------- sparse MoE mat1 (BK=64, XCD-swizzled) ------------------------------
__global__ __launch_bounds__(256, 3) void moe_mat1_kernel(
    const bf16* __restrict__ A, const void* __restrict__ Wt, size_t woff,
    const void* __restrict__ bias, size_t boff, bf16* __restrict__ hid,
    const int* __restrict__ off, const int* __restrict__ endp,
    const int* __restrict__ pack, const float* __restrict__ wlist,
    const int* __restrict__ flag) {
  const int wbf = flag[0];
  // swizzle over (x=8, y=256): xcd-clustered tile assignment
  int id = blockIdx.x + 8 * blockIdx.y;
  int g = (id & 7) * 256 + (id >> 3);
  const int n0 = (g & 7) * 128;
  int gy = g >> 3;
  const int e = gy >> 6, mt = gy & 63;
  const int o = off[e], en = endp[e];
  if (mt * 128 >= en - o) return;
  __shared__ bf16 As[128][64];
  __shared__ bf16 Bs[128][64];
  const int tid = threadIdx.x;
  const int ln = tid & 63, wv = tid >> 6;
  const int m0 = o + mt * 128;
  const int wr = (wv >> 1) * 64, wc = (wv & 1) * 64;
  const int mrow = ln & 15, quad = ln >> 4;
  const int sr8 = ln >> 3;
  const int sk8 = (ln & 7) * 8;
  // gather source tokens for this thread's four staged rows
  int tokr[4];
#pragma unroll
  for (int j = 0; j < 4; j++) {
    int pos = m0 + (4 * j + wv) * 8 + sr8;
    tokr[j] = pack[min(pos, en - 1)] >> 1;
  }

  f32x4 acc[4][4];
#pragma unroll
  for (int i = 0; i < 4; i++)
#pragma unroll
    for (int j = 0; j < 4; j++) acc[i][j] = (f32x4){0.f, 0.f, 0.f, 0.f};

  const size_t wbase = woff + (size_t)e * 1024 * 512;
  for (int k0 = 0; k0 < 512; k0 += 64) {
#pragma unroll
    for (int j = 0; j < 4; j++)
      gload16(A + (size_t)tokr[j] * 512 + k0 + sk8,
              (char*)&As[0][0] + (size_t)(4 * j + wv) * 1024);
#pragma unroll
    for (int j = 0; j < 4; j++) {
      int row = (4 * j + wv) * 8 + sr8;
      size_t baddr = wbase + (size_t)(n0 + row) * 512 + k0 + sk8;
      if (wbf) {
        gload16((const bf16*)Wt + baddr, (char*)&Bs[0][0] + (size_t)(4 * j + wv) * 1024);
      } else {
        const float* gp = (const float*)Wt + baddr;
        short8 v;
#pragma unroll
        for (int u = 0; u < 8; u++) { bf16 t = __float2bfloat16(gp[u]); v[u] = *(short*)&t; }
        *(short8*)&Bs[row][sk8] = v;
      }
    }
    __syncthreads();
#pragma unroll
    for (int ks = 0; ks < 2; ks++) {
      short8 af[4], bfr[4];
#pragma unroll
      for (int t = 0; t < 4; t++) {
        af[t]  = *(const short8*)&As[wr + t * 16 + mrow][quad * 8 + ks * 32];
        bfr[t] = *(const short8*)&Bs[wc + t * 16 + mrow][quad * 8 + ks * 32];
      }
#pragma unroll
      for (int i = 0; i < 4; i++)
#pragma unroll
        for (int j = 0; j < 4; j++)
          acc[i][j] = __builtin_amdgcn_mfma_f32_16x16x32_bf16(af[i], bfr[j], acc[i][j], 0, 0, 0);
    }
    __syncthreads();
  }

#pragma unroll
  for (int ti = 0; ti < 4; ti++) {
#pragma unroll
    for (int r = 0; r < 4; r++) {
      int pos = m0 + wr + ti * 16 + quad * 4 + r;
      float w = (pos < en) ? wlist[pos] : 0.f;
#pragma unroll
      for (int tj = 0; tj < 4; tj++) {
        int ncol = n0 + wc + tj * 16 + mrow;
        float v = acc[ti][tj][r] + ldin(bias, boff + e * 1024 + ncol, wbf);
        hid[(size_t)pos * 1024 + ncol] = __float2bfloat16(fmaxf(v, 0.f) * w);
      }
    }
  }
}

// ---------------- sparse MoE mat2 (BK=64, XCD-swizzled, split-K z=2) -----------------
__global__ __launch_bounds__(256, 3) void moe_mat2_kernel(
    const bf16* __restrict__ hid, const void* __restrict__ Wt, size_t woff,
    bf16* __restrict__ psl,
    const int* __restrict__ off, const int* __restrict__ endp,
    const int* __restrict__ pack, const int* __restrict__ flag) {
  const int wbf = flag[0];
  int id = blockIdx.x + 4 * blockIdx.y;
  int g = (id & 7) * 128 + (id >> 3);
  const int n0 = (g & 3) * 128;
  int gy = g >> 2;
  const int e = gy >> 6, mt = gy & 63;
  const int o = off[e], en = endp[e];
  if (mt * 128 >= en - o) return;
  __shared__ bf16 As[128][64];
  __shared__ bf16 Bs[128][64];
  const int tid = threadIdx.x;
  const int ln = tid & 63, wv = tid >> 6;
  const int m0 = o + mt * 128;
  const int wr = (wv >> 1) * 64, wc = (wv & 1) * 64;
  const int mrow = ln & 15, quad = ln >> 4;
  const int sr8 = ln >> 3;
  const int sk8 = (ln & 7) * 8;
  const int kbeg = blockIdx.z * 512;

  f32x4 acc[4][4];
#pragma unroll
  for (int i = 0; i < 4; i++)
#pragma unroll
    for (int j = 0; j < 4; j++) acc[i][j] = (f32x4){0.f, 0.f, 0.f, 0.f};

  const size_t wbase = woff + (size_t)e * 512 * 1024;
  for (int k0 = kbeg; k0 < kbeg + 512; k0 += 64) {
#pragma unroll
    for (int j = 0; j < 4; j++) {
      int row = (4 * j + wv) * 8 + sr8;
      gload16(hid + (size_t)(m0 + row) * 1024 + k0 + sk8,
              (char*)&As[0][0] + (size_t)(4 * j + wv) * 1024);
    }
#pragma unroll
    for (int j = 0; j < 4; j++) {
      int row = (4 * j + wv) * 8 + sr8;
      size_t baddr = wbase + (size_t)(n0 + row) * 1024 + k0 + sk8;
      if (wbf) {
        gload16((const bf16*)Wt + baddr, (char*)&Bs[0][0] + (size_t)(4 * j + wv) * 1024);
      } else {
        const float* gp = (const float*)Wt + baddr;
        short8 v;
#pragma unroll
        for (int u = 0; u < 8; u++) { bf16 t = __float2bfloat16(gp[u]); v[u] = *(short*)&t; }
        *(short8*)&Bs[row][sk8] = v;
      }
    }
    __syncthreads();
#pragma unroll
    for (int ks = 0; ks < 2; ks++) {
      short8 af[4], bfr[4];
#pragma unroll
      for (int t = 0; t < 4; t++) {
        af[t]  = *(const short8*)&As[wr + t * 16 + mrow][quad * 8 + ks * 32];
        bfr[t] = *(const short8*)&Bs[wc + t * 16 + mrow][quad * 8 + ks * 32];
      }
#pragma unroll
      for (int i = 0; i < 4; i++)
#pragma unroll
        for (int j = 0; j < 4; j++)
          acc[i][j] = __builtin_amdgcn_mfma_f32_16x16x32_bf16(af[i], bfr[j], acc[i][j], 0, 0, 0);
    }
    __syncthreads();
  }

#pragma unroll
  for (int ti = 0; ti < 4; ti++) {
#pragma unroll
    for (int r = 0; r < 4; r++) {
      int pos = m0 + wr + ti * 16 + quad * 4 + r;
      if (pos < en) {
        int pk = pack[pos];
        int tok = pk >> 1, rank = pk & 1;
        bf16* dst = psl + (size_t)(rank * 2 + blockIdx.z) * T_ * D_ + (size_t)tok * D_;
#pragma unroll
        for (int tj = 0; tj < 4; tj++) {
          int ncol = n0 + wc + tj * 16 + mrow;
          dst[ncol] = __float2bfloat16(acc[ti][tj][r]);
        }
      }
    }
  }
}

// ---------------- head ----------------
__global__ __launch_bounds__(256) void head_kernel(const float* __restrict__ hbuf,
                                                   const void* __restrict__ hw,
                                                   const void* __restrict__ hb,
                                                   void* __restrict__ out,
                                                   const int* __restrict__ flag) {
  const int bf = flag[0];
  int bq = blockIdx.x, tid = threadIdx.x;
  int b = bq / 3, q = bq % 3;
  __shared__ float red[256];
  const float* xr = hbuf + (size_t)(b * S_ + (S_ - 1)) * D_;
  float sacc = xr[tid] * ldin(hw, (size_t)q * D_ + tid, bf)
             + xr[tid + 256] * ldin(hw, (size_t)q * D_ + tid + 256, bf);
  red[tid] = sacc; __syncthreads();
  for (int w = 128; w; w >>= 1) { if (tid < w) red[tid] += red[tid + w]; __syncthreads(); }
  if (tid == 0) {
    float r = red[0] + ldin(hb, q, bf);
    if (bf) ((bf16*)out)[bq] = __float2bfloat16(r);
    else    ((float*)out)[bq] = r;
  }
}

extern "C" void kernel_launch(void* const* d_in, const int* in_sizes, int n_in,
                              void* d_out, int out_size, void* d_ws, size_t ws_size,
                              hipStream_t stream) {
  const void* x    = d_in[0];
  const void* Wp   = d_in[1];
  const void* bp   = d_in[2];
  const void* femb = d_in[3];
  const void* qkvw = d_in[4];
  const void* qkvb = d_in[5];
  const void* ow   = d_in[6];
  const void* ob   = d_in[7];
  const void* g1   = d_in[8];
  const void* be1  = d_in[9];
  const void* gw   = d_in[10];
  const void* gb   = d_in[11];
  const void* ew1  = d_in[12];
  const void* eb1  = d_in[13];
  const void* ew2  = d_in[14];
  const void* eb2  = d_in[15];
  const void* g2   = d_in[16];
  const void* be2  = d_in[17];
  const void* hw   = d_in[18];
  const void* hb   = d_in[19];
  const int*  freq = (const int*)d_in[20];

  // workspace layout: ~90 MB peak (proven-safe bound: 101 MB)
  int*   flag  = (int*)d_ws;                        // 64 ints
  int*   off   = flag + 64;                         // 4
  int*   endp  = off + 4;                           // 4
  int*   cur   = endp + 4;                          // 4 (+pad to 64)
  int*   einfo = flag + 128;                        // T ints
  float* w0a   = (float*)(einfo + T_);              // T
  float* w1a   = w0a + T_;                          // T
  int*   pack  = (int*)(w1a + T_);                  // CAP ints
  float* wlist = (float*)(pack + CAP_);             // CAP
  float* xn    = wlist + CAP_;                      // 65536
  float* h     = xn + 65536;                        // T*D f    (16 MB)
  float* cw    = h + (size_t)T_ * D_;               // T*4
  bf16*  hb16  = (bf16*)(cw + (size_t)T_ * E_);     // T*D bf16 (8 MB)
  bf16*  R     = hb16 + (size_t)T_ * D_;            // alias region: max(qkv+ao, hid) = 33 MB
  bf16*  qkvb16 = R;                                // T*3D bf16 (24 MB)
  bf16*  ao    = R + (size_t)T_ * D3_;              // T*D bf16  (8 MB)
  bf16*  hid   = R;                                 // CAP*1024 bf16 (~33 MB)
  bf16*  psl   = R + (size_t)CAP_ * 1024;           // 4x T*D bf16 (32 MB partial slices)

  detect_kernel<<<1, 64, 0, stream>>>(x, flag);
  instnorm_kernel<<<B_ * F_, 256, 0, stream>>>(x, xn, flag);
  input_proj_kernel<<<(T_ * D_) / 256, 256, 0, stream>>>(xn, Wp, bp, femb, freq, h, hb16, flag);

  for (int l = 0; l < 3; l++) {
    // QKV projection -> bf16
    mfma_gemm<3><<<dim3(D3_ / 128, T_ / 128), 256, 0, stream>>>(
        hb16, qkvw, (size_t)l * D3_ * D_, qkvb, (size_t)l * D3_, qkvb16,
        D_, D_, D_, D3_, flag);
    attn_kernel<<<B_ * H_ * (S_ / 128), 256, 0, stream>>>(qkvb16, ao);
    // O-projection: split-K=2 -> slices 0,1; fused reduce + bias + LN
    mfma_gemm<0><<<dim3(D_ / 128, T_ / 128, 2), 256, 0, stream>>>(
        ao, ow, (size_t)l * D_ * D_, nullptr, 0, psl,
        D_, D_, D_, D_, flag);
    reduce_ln_kernel<<<T_, 256, 0, stream>>>(
        h, hb16, psl, 2, 0, ob, (size_t)l * D_, nullptr, nullptr, 0,
        g1, be1, (size_t)l * D_, flag);
    // gating + routing
    gate_kernel<<<T_ / 4, 256, 0, stream>>>(h, gw, (size_t)l * E_ * D_, gb, (size_t)l * E_,
                                            cw, einfo, w0a, w1a, flag);
    route_scan_kernel<<<1, 256, 0, stream>>>(einfo, off, endp, cur);
    scatter_kernel<<<T_ / 256, 256, 0, stream>>>(einfo, w0a, w1a, off, cur, pack, wlist);
    // sparse expert GEMMs (hid aliases qkv+ao, both dead here)
    moe_mat1_kernel<<<dim3(8, 256), 256, 0, stream>>>(
        hb16, ew1, (size_t)l * E_ * 1024 * 512, eb1, (size_t)l * E_ * 1024, hid,
        off, endp, pack, wlist, flag);
    moe_mat2_kernel<<<dim3(4, 256, 2), 256, 0, stream>>>(
        hid, ew2, (size_t)l * E_ * 512 * 1024, psl, off, endp, pack, flag);
    reduce_ln_kernel<<<T_, 256, 0, stream>>>(
        h, hb16, psl, 4, 1, nullptr, 0, cw, eb2, (size_t)l * E_ * D_,
        g2, be2, (size_t)l * D_, flag);
  }

  head_kernel<<<24, 256, 0, stream>>>(h, hw, hb, d_out, flag);
}

// Round 10
// 1134.079 us; speedup vs baseline: 1.1514x; 1.1514x over previous
//
#include <hip/hip_runtime.h>
#include <hip/hip_bf16.h>
#include <math.h>

typedef __hip_bfloat16 bf16;
typedef __attribute__((ext_vector_type(8))) short short8;   // 8 bf16 (4 VGPRs)
typedef __attribute__((ext_vector_type(4))) float f32x4;

constexpr int B_ = 8, S_ = 1024, F_ = 8, D_ = 512, H_ = 8, E_ = 4;
constexpr int T_  = B_ * S_;       // 8192 tokens
constexpr int D3_ = 3 * D_;        // 1536
constexpr int CAP_ = T_ * 2 + E_ * 128;   // sparse row capacity (top-2, 128-pad/expert)

__device__ __forceinline__ float b2f(bf16 v) { return __bfloat162float(v); }
__device__ __forceinline__ float ldin(const void* p, size_t i, int bf) {
  return bf ? __bfloat162float(((const bf16*)p)[i]) : ((const float*)p)[i];
}
__device__ __forceinline__ void gload16(const void* g, void* l) {
  __builtin_amdgcn_global_load_lds((const __attribute__((address_space(1))) unsigned int*)g,
                                   (__attribute__((address_space(3))) unsigned int*)l, 16, 0, 0);
}

// ---------------- dtype detector ----------------
__global__ void detect_kernel(const void* __restrict__ x, int* __restrict__ flag) {
  if (threadIdx.x == 0 && blockIdx.x == 0) {
    const unsigned short* u = (const unsigned short*)x;
    int c = 0;
    for (int i = 0; i < 256; i += 2) {
      int ex = (u[i] >> 7) & 0xFF;
      if (ex >= 96 && ex <= 144) c++;
    }
    flag[0] = (c >= 64) ? 1 : 0;
  }
}

// ---------------- instance norm over time axis ----------------
__global__ __launch_bounds__(256) void instnorm_kernel(const void* __restrict__ x,
                                                       float* __restrict__ xn,
                                                       const int* __restrict__ flag) {
  const int bf = flag[0];
  int b = blockIdx.x / F_, f = blockIdx.x % F_;
  int tid = threadIdx.x;
  __shared__ float red[256];
  const int base = b * S_ * F_ + f;
  float s = 0.f;
  for (int j = tid; j < S_; j += 256) s += ldin(x, base + j * F_, bf);
  red[tid] = s; __syncthreads();
  for (int w = 128; w; w >>= 1) { if (tid < w) red[tid] += red[tid + w]; __syncthreads(); }
  float mean = red[0] / S_;
  __syncthreads();
  float v = 0.f;
  for (int j = tid; j < S_; j += 256) { float d = ldin(x, base + j * F_, bf) - mean; v += d * d; }
  red[tid] = v; __syncthreads();
  for (int w = 128; w; w >>= 1) { if (tid < w) red[tid] += red[tid + w]; __syncthreads(); }
  float inv = 1.f / (sqrtf(red[0] / (float)(S_ - 1)) + 1e-5f);
  for (int j = tid; j < S_; j += 256) xn[base + j * F_] = (ldin(x, base + j * F_, bf) - mean) * inv;
}

// ---------------- input projection + freq emb + positional encoding ----------------
__global__ __launch_bounds__(256) void input_proj_kernel(const float* __restrict__ xn,
                                                         const void* __restrict__ Wp,
                                                         const void* __restrict__ bp,
                                                         const void* __restrict__ femb,
                                                         const int* __restrict__ freq_idx,
                                                         float* __restrict__ h,
                                                         bf16* __restrict__ hb16,
                                                         const int* __restrict__ flag) {
  const int bf = flag[0];
  int idx = blockIdx.x * 256 + threadIdx.x;
  int d = idx % D_;
  int t = idx / D_;
  int s = t % S_;
  int fi = freq_idx[0];
  float acc = ldin(bp, d, bf) + ldin(femb, (size_t)fi * D_ + d, bf);
  int i2 = d & ~1;
  const float cexp = -9.2103403719761836f / (float)D_;
  float ang = (float)s * expf((float)i2 * cexp);
  acc += (d & 1) ? cosf(ang) : sinf(ang);
  const float* xr = xn + t * F_;
#pragma unroll
  for (int f = 0; f < F_; f++) acc += xr[f] * ldin(Wp, (size_t)d * F_ + f, bf);
  h[idx] = acc;
  hb16[idx] = __float2bfloat16(acc);
}

// ---------------- dense MFMA GEMM, BK=32, XCD-clustered swizzle ----------------
// MODE 3: C bf16 = acc + bias  (QKV). MODE 0: partial bf16 slice per z (O-proj).
// Requires gridDim.y % 8 == 0 for the swizzle.
template <int MODE>
__global__ __launch_bounds__(256) void mfma_gemm(
    const bf16* __restrict__ A, const void* __restrict__ Wt, size_t woff,
    const void* __restrict__ bias, size_t boff, void* __restrict__ C_,
    int Kd, int lda, int ldb, int ldc, const int* __restrict__ flag) {
  const int wbf = flag[0];
  __shared__ bf16 As[128][32];
  __shared__ bf16 Bs[128][32];
  const int tid = threadIdx.x;
  const int ln = tid & 63, wv = tid >> 6;
  // XCD-cluster swizzle: all x-tiles of a y-tile land on one XCD (xcd = linear id % 8)
  int id = blockIdx.x + gridDim.x * blockIdx.y;
  int xcd = id & 7, idq = id >> 3;
  const int n0 = (idq % gridDim.x) * 128;
  const int m0 = (xcd + 8 * (idq / gridDim.x)) * 128;
  const int wr = (wv >> 1) * 64, wc = (wv & 1) * 64;
  const int mrow = ln & 15, quad = ln >> 4;
  const int srow = ln >> 2;
  const int skof = (ln & 3) * 8;
  const int kchunk = Kd / gridDim.z;
  const int kbeg = blockIdx.z * kchunk;

  f32x4 acc[4][4];
#pragma unroll
  for (int i = 0; i < 4; i++)
#pragma unroll
    for (int j = 0; j < 4; j++) acc[i][j] = (f32x4){0.f, 0.f, 0.f, 0.f};

  for (int k0 = kbeg; k0 < kbeg + kchunk; k0 += 32) {
#pragma unroll
    for (int j = 0; j < 2; j++) {
      int row = 16 * (4 * j + wv) + srow;
      gload16(A + (size_t)(m0 + row) * lda + k0 + skof,
              (char*)&As[0][0] + (size_t)(4 * j + wv) * 1024);
    }
#pragma unroll
    for (int j = 0; j < 2; j++) {
      int row = 16 * (4 * j + wv) + srow;
      size_t baddr = woff + (size_t)(n0 + row) * ldb + k0 + skof;
      if (wbf) {
        gload16((const bf16*)Wt + baddr, (char*)&Bs[0][0] + (size_t)(4 * j + wv) * 1024);
      } else {
        const float* gp = (const float*)Wt + baddr;
        short8 v;
#pragma unroll
        for (int u = 0; u < 8; u++) { bf16 t = __float2bfloat16(gp[u]); v[u] = *(short*)&t; }
        *(short8*)&Bs[row][skof] = v;
      }
    }
    __syncthreads();
    short8 af[4], bfr[4];
#pragma unroll
    for (int t = 0; t < 4; t++) {
      af[t]  = *(const short8*)&As[wr + t * 16 + mrow][quad * 8];
      bfr[t] = *(const short8*)&Bs[wc + t * 16 + mrow][quad * 8];
    }
#pragma unroll
    for (int i = 0; i < 4; i++)
#pragma unroll
      for (int j = 0; j < 4; j++)
        acc[i][j] = __builtin_amdgcn_mfma_f32_16x16x32_bf16(af[i], bfr[j], acc[i][j], 0, 0, 0);
    __syncthreads();
  }

  bf16* slice = (MODE == 0) ? (bf16*)C_ + (size_t)blockIdx.z * T_ * D_ : (bf16*)C_;
#pragma unroll
  for (int tj = 0; tj < 4; tj++) {
    int n = n0 + wc + tj * 16 + mrow;
    float bv = (MODE == 3) ? ldin(bias, boff + n, wbf) : 0.f;
#pragma unroll
    for (int ti = 0; ti < 4; ti++) {
      int mbase = m0 + wr + ti * 16 + quad * 4;
#pragma unroll
      for (int r = 0; r < 4; r++) {
        int m = mbase + r;
        float v = acc[ti][tj][r];
        slice[(size_t)m * ldc + n] = __float2bfloat16(MODE == 3 ? v + bv : v);
      }
    }
  }
}

// ---------------- MFMA flash attention: 128-query tile, swizzled V transpose --------
__global__ __launch_bounds__(256) void attn_kernel(const bf16* __restrict__ qkv,
                                                   bf16* __restrict__ o) {
  __shared__ bf16 Qs[128][72];
  __shared__ bf16 Ks[64][72];
  __shared__ bf16 Vt[64][72];    // [d][k ^ swz(d)]
  __shared__ bf16 Ps[128][72];   // [q][k]
  const int tid = threadIdx.x;
  const int ln = tid & 63, wv = tid >> 6;
  const int mrow = ln & 15, quad = ln >> 4;
  const int qt = blockIdx.x & 7, hh = (blockIdx.x >> 3) & 7, b = blockIdx.x >> 6;
  const int q0 = qt * 128;
  const int sr = tid >> 2;          // staging row 0..63
  const int sg = tid & 3;           // staging col group
  const int sc = sg * 8;            // staging col base; chunks at sc, sc+32

#pragma unroll
  for (int p = 0; p < 2; p++) {
    int row = sr + p * 64;
    const bf16* src = qkv + (size_t)(b * S_ + q0 + row) * D3_ + hh * 64;
    *(short8*)&Qs[row][sc]      = *(const short8*)(src + sc);
    *(short8*)&Qs[row][sc + 32] = *(const short8*)(src + sc + 32);
  }
  __syncthreads();
  short8 aq[2][2];
#pragma unroll
  for (int g = 0; g < 2; g++) {
    aq[g][0] = *(const short8*)&Qs[wv * 32 + g * 16 + mrow][quad * 8];
    aq[g][1] = *(const short8*)&Qs[wv * 32 + g * 16 + mrow][quad * 8 + 32];
  }

  float m_st[2][4], l_st[2][4];
  f32x4 oacc[2][4];
#pragma unroll
  for (int g = 0; g < 2; g++)
#pragma unroll
    for (int t = 0; t < 4; t++) {
      m_st[g][t] = -1e30f; l_st[g][t] = 0.f;
      oacc[g][t] = (f32x4){0.f, 0.f, 0.f, 0.f};
    }

  for (int kt = 0; kt < 16; kt++) {
    int k0 = kt * 64;
    __syncthreads();
    {
      const bf16* src = qkv + (size_t)(b * S_ + k0 + sr) * D3_ + D_ + hh * 64;
      *(short8*)&Ks[sr][sc]      = *(const short8*)(src + sc);
      *(short8*)&Ks[sr][sc + 32] = *(const short8*)(src + sc + 32);
    }
    {
      const bf16* src = qkv + (size_t)(b * S_ + k0 + sr) * D3_ + 2 * D_ + hh * 64;
      short8 v0 = *(const short8*)(src + sc);
      short8 v1 = *(const short8*)(src + sc + 32);
      int col0 = sr ^ (sg << 4);
      int col1 = sr ^ (((sg + 4) & 3) << 4);
#pragma unroll
      for (int u = 0; u < 8; u++) {
        *(short*)&Vt[sc + u][col0]      = v0[u];
        *(short*)&Vt[sc + 32 + u][col1] = v1[u];
      }
    }
    __syncthreads();
    f32x4 s[2][4];
#pragma unroll
    for (int g = 0; g < 2; g++)
#pragma unroll
      for (int t = 0; t < 4; t++) {
        s[g][t] = (f32x4){0.f, 0.f, 0.f, 0.f};
#pragma unroll
        for (int ks = 0; ks < 2; ks++) {
          short8 bk = *(const short8*)&Ks[t * 16 + mrow][quad * 8 + ks * 32];
          s[g][t] = __builtin_amdgcn_mfma_f32_16x16x32_bf16(aq[g][ks], bk, s[g][t], 0, 0, 0);
        }
      }
#pragma unroll
    for (int g = 0; g < 2; g++)
#pragma unroll
      for (int r = 0; r < 4; r++) {
        float rm = fmaxf(fmaxf(s[g][0][r], s[g][1][r]), fmaxf(s[g][2][r], s[g][3][r])) * 0.125f;
#pragma unroll
        for (int off = 8; off; off >>= 1) rm = fmaxf(rm, __shfl_xor(rm, off, 64));
        float mnew = fmaxf(m_st[g][r], rm);
        float alpha = __expf(m_st[g][r] - mnew);
        m_st[g][r] = mnew;
        float rs = 0.f;
#pragma unroll
        for (int t = 0; t < 4; t++) {
          float p = __expf(s[g][t][r] * 0.125f - mnew);
          rs += p;
          Ps[wv * 32 + g * 16 + quad * 4 + r][t * 16 + mrow] = __float2bfloat16(p);
        }
#pragma unroll
        for (int off = 8; off; off >>= 1) rs += __shfl_xor(rs, off, 64);
        l_st[g][r] = l_st[g][r] * alpha + rs;
#pragma unroll
        for (int t = 0; t < 4; t++) oacc[g][t][r] *= alpha;
      }
#pragma unroll
    for (int g = 0; g < 2; g++) {
      short8 ap[2];
      ap[0] = *(const short8*)&Ps[wv * 32 + g * 16 + mrow][quad * 8];
      ap[1] = *(const short8*)&Ps[wv * 32 + g * 16 + mrow][quad * 8 + 32];
#pragma unroll
      for (int t = 0; t < 4; t++) {
        int d = t * 16 + mrow;
        int swz = ((d >> 3) & 3) << 4;
#pragma unroll
        for (int ks = 0; ks < 2; ks++) {
          short8 bv = *(const short8*)&Vt[d][(quad * 8 + ks * 32) ^ swz];
          oacc[g][t] = __builtin_amdgcn_mfma_f32_16x16x32_bf16(ap[ks], bv, oacc[g][t], 0, 0, 0);
        }
      }
    }
  }
#pragma unroll
  for (int g = 0; g < 2; g++)
#pragma unroll
    for (int r = 0; r < 4; r++) {
      float inv = 1.f / l_st[g][r];
      size_t base = (size_t)(b * S_ + q0 + wv * 32 + g * 16 + quad * 4 + r) * D_ + hh * 64;
#pragma unroll
      for (int t = 0; t < 4; t++)
        o[base + t * 16 + mrow] = __float2bfloat16(oacc[g][t][r] * inv);
    }
}

// ---------------- fused: sum partial slices + bias + residual + LayerNorm ----------
__global__ __launch_bounds__(256) void reduce_ln_kernel(float* __restrict__ h,
                                                        bf16* __restrict__ hb16,
                                                        const bf16* __restrict__ ps,
                                                        int nsl, int mode,
                                                        const void* __restrict__ bias,
                                                        size_t boff,
                                                        const float* __restrict__ cw,
                                                        const void* __restrict__ eb2p,
                                                        size_t e2off,
                                                        const void* __restrict__ g,
                                                        const void* __restrict__ beta,
                                                        size_t off,
                                                        const int* __restrict__ flag) {
  const int bf = flag[0];
  int t = blockIdx.x, tid = threadIdx.x;
  __shared__ float r1[256], r2[256];
  const size_t base = (size_t)t * D_;
  float o0 = 0.f, o1 = 0.f;
  for (int s = 0; s < nsl; s++) {
    o0 += b2f(ps[(size_t)s * T_ * D_ + base + tid]);
    o1 += b2f(ps[(size_t)s * T_ * D_ + base + tid + 256]);
  }
  if (mode == 0) {
    o0 += ldin(bias, boff + tid, bf);
    o1 += ldin(bias, boff + tid + 256, bf);
  } else {
#pragma unroll
    for (int e = 0; e < 4; e++) {
      float w = cw[t * 4 + e];
      o0 += w * ldin(eb2p, e2off + e * D_ + tid, bf);
      o1 += w * ldin(eb2p, e2off + e * D_ + tid + 256, bf);
    }
  }
  float* hr = h + base;
  float v0 = hr[tid] + o0;
  float v1 = hr[tid + 256] + o1;
  r1[tid] = v0 + v1;
  r2[tid] = v0 * v0 + v1 * v1;
  __syncthreads();
  for (int w = 128; w; w >>= 1) { if (tid < w) { r1[tid] += r1[tid + w]; r2[tid] += r2[tid + w]; } __syncthreads(); }
  float mean = r1[0] * (1.f / D_);
  float var  = r2[0] * (1.f / D_) - mean * mean;
  float rstd = rsqrtf(var + 1e-5f);
  float n0 = (v0 - mean) * rstd * ldin(g, off + tid, bf) + ldin(beta, off + tid, bf);
  float n1 = (v1 - mean) * rstd * ldin(g, off + tid + 256, bf) + ldin(beta, off + tid + 256, bf);
  hr[tid] = n0;
  hr[tid + 256] = n1;
  hb16[base + tid] = __float2bfloat16(n0);
  hb16[base + tid + 256] = __float2bfloat16(n1);
}

// ---------------- MoE gating: softmax over E=4, top-2; emits routing info ----------
__global__ __launch_bounds__(256) void gate_kernel(const float* __restrict__ hbuf,
                                                   const void* __restrict__ gw, size_t gwoff,
                                                   const void* __restrict__ gb, size_t gboff,
                                                   float* __restrict__ cw,
                                                   int* __restrict__ einfo,
                                                   float* __restrict__ w0a,
                                                   float* __restrict__ w1a,
                                                   const int* __restrict__ flag) {
  const int bf = flag[0];
  int lane = threadIdx.x & 63, wv = threadIdx.x >> 6;
  int t = blockIdx.x * 4 + wv;
  const float* xr = hbuf + (size_t)t * D_;
  float a[4] = {0, 0, 0, 0};
  for (int d = lane; d < D_; d += 64) {
    float xv = xr[d];
#pragma unroll
    for (int e = 0; e < 4; e++) a[e] += xv * ldin(gw, gwoff + e * D_ + d, bf);
  }
#pragma unroll
  for (int e = 0; e < 4; e++)
    for (int off = 32; off; off >>= 1) a[e] += __shfl_xor(a[e], off, 64);
  if (lane == 0) {
    float lg[4];
#pragma unroll
    for (int e = 0; e < 4; e++) lg[e] = a[e] + ldin(gb, gboff + e, bf);
    float m = fmaxf(fmaxf(lg[0], lg[1]), fmaxf(lg[2], lg[3]));
    float p[4], s = 0.f;
#pragma unroll
    for (int e = 0; e < 4; e++) { p[e] = __expf(lg[e] - m); s += p[e]; }
#pragma unroll
    for (int e = 0; e < 4; e++) p[e] /= s;
    int i0 = 0;
    for (int e = 1; e < 4; e++) if (p[e] > p[i0]) i0 = e;
    int i1 = -1;
    for (int e = 0; e < 4; e++) if (e != i0 && (i1 < 0 || p[e] > p[i1])) i1 = e;
    float s2 = p[i0] + p[i1];
    float ww0 = p[i0] / s2, ww1 = p[i1] / s2;
    float outw[4] = {0, 0, 0, 0};
    outw[i0] = ww0; outw[i1] = ww1;
#pragma unroll
    for (int e = 0; e < 4; e++) cw[t * 4 + e] = outw[e];
    einfo[t] = i0 | (i1 << 4);
    w0a[t] = ww0; w1a[t] = ww1;
  }
}

// ---------------- route scan: counts -> offsets + tile table (1 block) ----------------
__global__ __launch_bounds__(256) void route_scan_kernel(const int* __restrict__ einfo,
                                                         int* __restrict__ off,
                                                         int* __restrict__ endp,
                                                         int* __restrict__ cur,
                                                         int* __restrict__ tmap) {
  __shared__ int red[4][256];
  int tid = threadIdx.x;
  int c[4] = {0, 0, 0, 0};
  for (int t = tid; t < T_; t += 256) {
    int inf = einfo[t];
    c[inf & 15]++;
    c[(inf >> 4) & 15]++;
  }
#pragma unroll
  for (int e = 0; e < 4; e++) red[e][tid] = c[e];
  __syncthreads();
  for (int w = 128; w; w >>= 1) {
    if (tid < w)
#pragma unroll
      for (int e = 0; e < 4; e++) red[e][tid] += red[e][tid + w];
    __syncthreads();
  }
  if (tid == 0) {
    int o = 0, idx = 0;
#pragma unroll
    for (int e = 0; e < 4; e++) {
      int cnt = red[e][0];
      off[e] = o;
      endp[e] = o + cnt;
      cur[e] = 0;
      int nt = (cnt + 127) >> 7;
      for (int i = 0; i < nt; i++) tmap[1 + idx++] = e | (i << 8);
      o += nt << 7;
    }
    tmap[0] = idx;   // total active m-tiles (<= 131)
  }
}

// ---------------- scatter: token -> (expert bucket, rank), ballot-aggregated --------
__global__ __launch_bounds__(256) void scatter_kernel(const int* __restrict__ einfo,
                                                      const float* __restrict__ w0a,
                                                      const float* __restrict__ w1a,
                                                      const int* __restrict__ off,
                                                      int* __restrict__ cur,
                                                      int* __restrict__ pack,
                                                      float* __restrict__ wlist) {
  int t = blockIdx.x * 256 + threadIdx.x;
  int lane = threadIdx.x & 63;
  int inf = einfo[t];
#pragma unroll
  for (int rank = 0; rank < 2; rank++) {
    int my_e = (rank == 0) ? (inf & 15) : ((inf >> 4) & 15);
    float w = (rank == 0) ? w0a[t] : w1a[t];
#pragma unroll
    for (int e = 0; e < 4; e++) {
      bool p = (my_e == e);
      unsigned long long mask = __ballot(p);
      if (!mask) continue;
      int leader = __ffsll((long long)mask) - 1;
      int base = 0;
      if (lane == leader) base = atomicAdd(&cur[e], (int)__popcll(mask));
      base = __shfl(base, leader, 64);
      if (p) {
        int pos = off[e] + base + (int)__popcll(mask & ((1ULL << lane) - 1ULL));
        pack[pos] = t * 2 + rank;
        wlist[pos] = w;
      }
    }
  }
}

// ---------------- sparse MoE mat1 (BK=32, tile-table, XCD-swizzled) ------------------
__global__ __launch_bounds__(256) void moe_mat1_kernel(
    const bf16* __restrict__ A, const void* __restrict__ Wt, size_t woff,
    const void* __restrict__ bias, size_t boff, bf16* __restrict__ hid,
    const int* __restrict__ off, const int* __restrict__ endp,
    const int* __restrict__ pack, const float* __restrict__ wlist,
    const int* __restrict__ tmap, const int* __restrict__ flag) {
  const int wbf = flag[0];
  // XCD-cluster swizzle over grid (8, 136)
  int id = blockIdx.x + 8 * blockIdx.y;
  int xcd = id & 7, idq = id >> 3;
  int wx = idq & 7, wy = xcd + 8 * (idq >> 3);
  if (wy >= tmap[0]) return;
  int ent = tmap[1 + wy];
  const int e = ent & 255, mt = ent >> 8;
  const int o = off[e], en = endp[e];
  const int n0 = wx * 128;
  __shared__ bf16 As[128][32];
  __shared__ bf16 Bs[128][32];
  const int tid = threadIdx.x;
  const int ln = tid & 63, wv = tid >> 6;
  const int m0 = o + mt * 128;
  const int wr = (wv >> 1) * 64, wc = (wv & 1) * 64;
  const int mrow = ln & 15, quad = ln >> 4;
  const int srow = ln >> 2;
  const int skof = (ln & 3) * 8;
  int tokr[2];
#pragma unroll
  for (int j = 0; j < 2; j++) {
    int pos = m0 + 16 * (4 * j + wv) + srow;
    tokr[j] = pack[min(pos, en - 1)] >> 1;
  }

  f32x4 acc[4][4];
#pragma unroll
  for (int i = 0; i < 4; i++)
#pragma unroll
    for (int j = 0; j < 4; j++) acc[i][j] = (f32x4){0.f, 0.f, 0.f, 0.f};

  const size_t wbase = woff + (size_t)e * 1024 * 512;
  for (int k0 = 0; k0 < 512; k0 += 32) {
#pragma unroll
    for (int j = 0; j < 2; j++)
      gload16(A + (size_t)tokr[j] * 512 + k0 + skof,
              (char*)&As[0][0] + (size_t)(4 * j + wv) * 1024);
#pragma unroll
    for (int j = 0; j < 2; j++) {
      int row = 16 * (4 * j + wv) + srow;
      size_t baddr = wbase + (size_t)(n0 + row) * 512 + k0 + skof;
      if (wbf) {
        gload16((const bf16*)Wt + baddr, (char*)&Bs[0][0] + (size_t)(4 * j + wv) * 1024);
      } else {
        const float* gp = (const float*)Wt + baddr;
        short8 v;
#pragma unroll
        for (int u = 0; u < 8; u++) { bf16 t = __float2bfloat16(gp[u]); v[u] = *(short*)&t; }
        *(short8*)&Bs[row][skof] = v;
      }
    }
    __syncthreads();
    short8 af[4], bfr[4];
#pragma unroll
    for (int t = 0; t < 4; t++) {
      af[t]  = *(const short8*)&As[wr + t * 16 + mrow][quad * 8];
      bfr[t] = *(const short8*)&Bs[wc + t * 16 + mrow][quad * 8];
    }
#pragma unroll
    for (int i = 0; i < 4; i++)
#pragma unroll
      for (int j = 0; j < 4; j++)
        acc[i][j] = __builtin_amdgcn_mfma_f32_16x16x32_bf16(af[i], bfr[j], acc[i][j], 0, 0, 0);
    __syncthreads();
  }

#pragma unroll
  for (int ti = 0; ti < 4; ti++) {
#pragma unroll
    for (int r = 0; r < 4; r++) {
      int pos = m0 + wr + ti * 16 + quad * 4 + r;
      float w = (pos < en) ? wlist[pos] : 0.f;
#pragma unroll
      for (int tj = 0; tj < 4; tj++) {
        int ncol = n0 + wc + tj * 16 + mrow;
        float v = acc[ti][tj][r] + ldin(bias, boff + e * 1024 + ncol, wbf);
        hid[(size_t)pos * 1024 + ncol] = __float2bfloat16(fmaxf(v, 0.f) * w);
      }
    }
  }
}

// ---------------- sparse MoE mat2 (BK=32, tile-table, XCD-swizzled, split-K z=2) -----
__global__ __launch_bounds__(256) void moe_mat2_kernel(
    const bf16* __restrict__ hid, const void* __restrict__ Wt, size_t woff,
    bf16* __restrict__ psl,
    const int* __restrict__ off, const int* __restrict__ endp,
    const int* __restrict__ pack, const int* __restrict__ tmap,
    const int* __restrict__ flag) {
  const int wbf = flag[0];
  // XCD-cluster swizzle over grid (4, 136)
  int id = blockIdx.x + 4 * blockIdx.y;
  int xcd = id & 7, idq = id >> 3;
  int wx = idq & 3, wy = xcd + 8 * (idq >> 2);
  if (wy >= tmap[0]) return;
  int ent = tmap[1 + wy];
  const int e = ent & 255, mt = ent >> 8;
  const int o = off[e], en = endp[e];
  const int n0 = wx * 128;
  __shared__ bf16 As[128][32];
  __shared__ bf16 Bs[128][32];
  const int tid = threadIdx.x;
  const int ln = tid & 63, wv = tid >> 6;
  const int m0 = o + mt * 128;
  const int wr = (wv >> 1) * 64, wc = (wv & 1) * 64;
  const int mrow = ln & 15, quad = ln >> 4;
  const int srow = ln >> 2;
  const int skof = (ln & 3) * 8;
  const int kbeg = blockIdx.z * 512;

  f32x4 acc[4][4];
#pragma unroll
  for (int i = 0; i < 4; i++)
#pragma unroll
    for (int j = 0; j < 4; j++) acc[i][j] = (f32x4){0.f, 0.f, 0.f, 0.f};

  const size_t wbase = woff + (size_t)e * 512 * 1024;
  for (int k0 = kbeg; k0 < kbeg + 512; k0 += 32) {
#pragma unroll
    for (int j = 0; j < 2; j++) {
      int row = 16 * (4 * j + wv) + srow;
      gload16(hid + (size_t)(m0 + row) * 1024 + k0 + skof,
              (char*)&As[0][0] + (size_t)(4 * j + wv) * 1024);
    }
#pragma unroll
    for (int j = 0; j < 2; j++) {
      int row = 16 * (4 * j + wv) + srow;
      size_t baddr = wbase + (size_t)(n0 + row) * 1024 + k0 + skof;
      if (wbf) {
        gload16((const bf16*)Wt + baddr, (char*)&Bs[0][0] + (size_t)(4 * j + wv) * 1024);
      } else {
        const float* gp = (const float*)Wt + baddr;
        short8 v;
#pragma unroll
        for (int u = 0; u < 8; u++) { bf16 t = __float2bfloat16(gp[u]); v[u] = *(short*)&t; }
        *(short8*)&Bs[row][skof] = v;
      }
    }
    __syncthreads();
    short8 af[4], bfr[4];
#pragma unroll
    for (int t = 0; t < 4; t++) {
      af[t]  = *(const short8*)&As[wr + t * 16 + mrow][quad * 8];
      bfr[t] = *(const short8*)&Bs[wc + t * 16 + mrow][quad * 8];
    }
#pragma unroll
    for (int i = 0; i < 4; i++)
#pragma unroll
      for (int j = 0; j < 4; j++)
        acc[i][j] = __builtin_amdgcn_mfma_f32_16x16x32_bf16(af[i], bfr[j], acc[i][j], 0, 0, 0);
    __syncthreads();
  }

#pragma unroll
  for (int ti = 0; ti < 4; ti++) {
#pragma unroll
    for (int r = 0; r < 4; r++) {
      int pos = m0 + wr + ti * 16 + quad * 4 + r;
      if (pos < en) {
        int pk = pack[pos];
        int tok = pk >> 1, rank = pk & 1;
        bf16* dst = psl + (size_t)(rank * 2 + blockIdx.z) * T_ * D_ + (size_t)tok * D_;
#pragma unroll
        for (int tj = 0; tj < 4; tj++) {
          int ncol = n0 + wc + tj * 16 + mrow;
          dst[ncol] = __float2bfloat16(acc[ti][tj][r]);
        }
      }
    }
  }
}

// ---------------- head ----------------
__global__ __launch_bounds__(256) void head_kernel(const float* __restrict__ hbuf,
                                                   const void* __restrict__ hw,
                                                   const void* __restrict__ hb,
                                                   void* __restrict__ out,
                                                   const int* __restrict__ flag) {
  const int bf = flag[0];
  int bq = blockIdx.x, tid = threadIdx.x;
  int b = bq / 3, q = bq % 3;
  __shared__ float red[256];
  const float* xr = hbuf + (size_t)(b * S_ + (S_ - 1)) * D_;
  float sacc = xr[tid] * ldin(hw, (size_t)q * D_ + tid, bf)
             + xr[tid + 256] * ldin(hw, (size_t)q * D_ + tid + 256, bf);
  red[tid] = sacc; __syncthreads();
  for (int w = 128; w; w >>= 1) { if (tid < w) red[tid] += red[tid + w]; __syncthreads(); }
  if (tid == 0) {
    float r = red[0] + ldin(hb, q, bf);
    if (bf) ((bf16*)out)[bq] = __float2bfloat16(r);
    else    ((float*)out)[bq] = r;
  }
}

extern "C" void kernel_launch(void* const* d_in, const int* in_sizes, int n_in,
                              void* d_out, int out_size, void* d_ws, size_t ws_size,
                              hipStream_t stream) {
  const void* x    = d_in[0];
  const void* Wp   = d_in[1];
  const void* bp   = d_in[2];
  const void* femb = d_in[3];
  const void* qkvw = d_in[4];
  const void* qkvb = d_in[5];
  const void* ow   = d_in[6];
  const void* ob   = d_in[7];
  const void* g1   = d_in[8];
  const void* be1  = d_in[9];
  const void* gw   = d_in[10];
  const void* gb   = d_in[11];
  const void* ew1  = d_in[12];
  const void* eb1  = d_in[13];
  const void* ew2  = d_in[14];
  const void* eb2  = d_in[15];
  const void* g2   = d_in[16];
  const void* be2  = d_in[17];
  const void* hw   = d_in[18];
  const void* hb   = d_in[19];
  const int*  freq = (const int*)d_in[20];

  // workspace layout: ~90 MB peak (proven-safe bound: 101 MB)
  int*   flag  = (int*)d_ws;                        // 64 ints
  int*   off   = flag + 64;                         // 4
  int*   endp  = off + 4;                           // 4
  int*   cur   = endp + 4;                          // 4 (+pad)
  int*   einfo = flag + 128;                        // T ints
  float* w0a   = (float*)(einfo + T_);              // T
  float* w1a   = w0a + T_;                          // T
  int*   pack  = (int*)(w1a + T_);                  // CAP ints
  float* wlist = (float*)(pack + CAP_);             // CAP
  int*   tmap  = (int*)(wlist + CAP_);              // 160 ints (count + tiles)
  float* xn    = (float*)(tmap + 160);              // 65536
  float* h     = xn + 65536;                        // T*D f    (16 MB)
  float* cw    = h + (size_t)T_ * D_;               // T*4
  bf16*  hb16  = (bf16*)(cw + (size_t)T_ * E_);     // T*D bf16 (8 MB)
  bf16*  R     = hb16 + (size_t)T_ * D_;            // alias region
  bf16*  qkvb16 = R;                                // T*3D bf16 (24 MB)
  bf16*  ao    = R + (size_t)T_ * D3_;              // T*D bf16  (8 MB)
  bf16*  hid   = R;                                 // CAP*1024 bf16 (~33 MB)
  bf16*  psl   = R + (size_t)CAP_ * 1024;           // 4x T*D bf16 (32 MB partial slices)

  detect_kernel<<<1, 64, 0, stream>>>(x, flag);
  instnorm_kernel<<<B_ * F_, 256, 0, stream>>>(x, xn, flag);
  input_proj_kernel<<<(T_ * D_) / 256, 256, 0, stream>>>(xn, Wp, bp, femb, freq, h, hb16, flag);

  for (int l = 0; l < 3; l++) {
    // QKV projection -> bf16
    mfma_gemm<3><<<dim3(D3_ / 128, T_ / 128), 256, 0, stream>>>(
        hb16, qkvw, (size_t)l * D3_ * D_, qkvb, (size_t)l * D3_, qkvb16,
        D_, D_, D_, D3_, flag);
    attn_kernel<<<B_ * H_ * (S_ / 128), 256, 0, stream>>>(qkvb16, ao);
    // O-projection: split-K=2 -> slices 0,1; fused reduce + bias + LN
    mfma_gemm<0><<<dim3(D_ / 128, T_ / 128, 2), 256, 0, stream>>>(
        ao, ow, (size_t)l * D_ * D_, nullptr, 0, psl,
        D_, D_, D_, D_, flag);
    reduce_ln_kernel<<<T_, 256, 0, stream>>>(
        h, hb16, psl, 2, 0, ob, (size_t)l * D_, nullptr, nullptr, 0,
        g1, be1, (size_t)l * D_, flag);
    // gating + routing
    gate_kernel<<<T_ / 4, 256, 0, stream>>>(h, gw, (size_t)l * E_ * D_, gb, (size_t)l * E_,
                                            cw, einfo, w0a, w1a, flag);
    route_scan_kernel<<<1, 256, 0, stream>>>(einfo, off, endp, cur, tmap);
    scatter_kernel<<<T_ / 256, 256, 0, stream>>>(einfo, w0a, w1a, off, cur, pack, wlist);
    // sparse expert GEMMs (hid aliases qkv+ao, both dead here)
    moe_mat1_kernel<<<dim3(8, 136), 256, 0, stream>>>(
        hb16, ew1, (size_t)l * E_ * 1024 * 512, eb1, (size_t)l * E_ * 1024, hid,
        off, endp, pack, wlist, tmap, flag);
    moe_mat2_kernel<<<dim3(4, 136, 2), 256, 0, stream>>>(
        hid, ew2, (size_t)l * E_ * 512 * 1024, psl, off, endp, pack, tmap, flag);
    reduce_ln_kernel<<<T_, 256, 0, stream>>>(
        h, hb16, psl, 4, 1, nullptr, 0, cw, eb2, (size_t)l * E_ * D_,
        g2, be2, (size_t)l * D_, flag);
  }

  head_kernel<<<24, 256, 0, stream>>>(h, hw, hb, d_out, flag);
}

// Round 11
// 1132.594 us; speedup vs baseline: 1.1529x; 1.0013x over previous
//
#include <hip/hip_runtime.h>
#include <hip/hip_bf16.h>
#include <math.h>

typedef __hip_bfloat16 bf16;
typedef __attribute__((ext_vector_type(8))) short short8;   // 8 bf16 (4 VGPRs)
typedef __attribute__((ext_vector_type(4))) float f32x4;

constexpr int B_ = 8, S_ = 1024, F_ = 8, D_ = 512, H_ = 8, E_ = 4;
constexpr int T_  = B_ * S_;       // 8192 tokens
constexpr int D3_ = 3 * D_;        // 1536
constexpr int CAP_ = T_ * 2 + E_ * 128;   // sparse row capacity (top-2, 128-pad/expert)

__device__ __forceinline__ float b2f(bf16 v) { return __bfloat162float(v); }
__device__ __forceinline__ float ldin(const void* p, size_t i, int bf) {
  return bf ? __bfloat162float(((const bf16*)p)[i]) : ((const float*)p)[i];
}
__device__ __forceinline__ void gload16(const void* g, void* l) {
  __builtin_amdgcn_global_load_lds((const __attribute__((address_space(1))) unsigned int*)g,
                                   (__attribute__((address_space(3))) unsigned int*)l, 16, 0, 0);
}

// ---------------- dtype detector ----------------
__global__ void detect_kernel(const void* __restrict__ x, int* __restrict__ flag) {
  if (threadIdx.x == 0 && blockIdx.x == 0) {
    const unsigned short* u = (const unsigned short*)x;
    int c = 0;
    for (int i = 0; i < 256; i += 2) {
      int ex = (u[i] >> 7) & 0xFF;
      if (ex >= 96 && ex <= 144) c++;
    }
    flag[0] = (c >= 64) ? 1 : 0;
  }
}

// ---------------- instance norm over time axis ----------------
__global__ __launch_bounds__(256) void instnorm_kernel(const void* __restrict__ x,
                                                       float* __restrict__ xn,
                                                       const int* __restrict__ flag) {
  const int bf = flag[0];
  int b = blockIdx.x / F_, f = blockIdx.x % F_;
  int tid = threadIdx.x;
  __shared__ float red[256];
  const int base = b * S_ * F_ + f;
  float s = 0.f;
  for (int j = tid; j < S_; j += 256) s += ldin(x, base + j * F_, bf);
  red[tid] = s; __syncthreads();
  for (int w = 128; w; w >>= 1) { if (tid < w) red[tid] += red[tid + w]; __syncthreads(); }
  float mean = red[0] / S_;
  __syncthreads();
  float v = 0.f;
  for (int j = tid; j < S_; j += 256) { float d = ldin(x, base + j * F_, bf) - mean; v += d * d; }
  red[tid] = v; __syncthreads();
  for (int w = 128; w; w >>= 1) { if (tid < w) red[tid] += red[tid + w]; __syncthreads(); }
  float inv = 1.f / (sqrtf(red[0] / (float)(S_ - 1)) + 1e-5f);
  for (int j = tid; j < S_; j += 256) xn[base + j * F_] = (ldin(x, base + j * F_, bf) - mean) * inv;
}

// ---------------- input projection + freq emb + positional encoding ----------------
__global__ __launch_bounds__(256) void input_proj_kernel(const float* __restrict__ xn,
                                                         const void* __restrict__ Wp,
                                                         const void* __restrict__ bp,
                                                         const void* __restrict__ femb,
                                                         const int* __restrict__ freq_idx,
                                                         float* __restrict__ h,
                                                         bf16* __restrict__ hb16,
                                                         const int* __restrict__ flag) {
  const int bf = flag[0];
  int idx = blockIdx.x * 256 + threadIdx.x;
  int d = idx % D_;
  int t = idx / D_;
  int s = t % S_;
  int fi = freq_idx[0];
  float acc = ldin(bp, d, bf) + ldin(femb, (size_t)fi * D_ + d, bf);
  int i2 = d & ~1;
  const float cexp = -9.2103403719761836f / (float)D_;
  float ang = (float)s * expf((float)i2 * cexp);
  acc += (d & 1) ? cosf(ang) : sinf(ang);
  const float* xr = xn + t * F_;
#pragma unroll
  for (int f = 0; f < F_; f++) acc += xr[f] * ldin(Wp, (size_t)d * F_ + f, bf);
  h[idx] = acc;
  hb16[idx] = __float2bfloat16(acc);
}

// ---------------- dense MFMA GEMM, BK=32, dbuf single-barrier K-loop, XCD swizzle ----
// MODE 3: C bf16 = acc + bias  (QKV). MODE 0: partial bf16 slice per z (O-proj).
// Requires gridDim.y % 8 == 0 for the swizzle.
template <int MODE>
__global__ __launch_bounds__(256) void mfma_gemm(
    const bf16* __restrict__ A, const void* __restrict__ Wt, size_t woff,
    const void* __restrict__ bias, size_t boff, void* __restrict__ C_,
    int Kd, int lda, int ldb, int ldc, const int* __restrict__ flag) {
  const int wbf = flag[0];
  __shared__ bf16 As[2][128][32];
  __shared__ bf16 Bs[2][128][32];
  const int tid = threadIdx.x;
  const int ln = tid & 63, wv = tid >> 6;
  int id = blockIdx.x + gridDim.x * blockIdx.y;
  int xcd = id & 7, idq = id >> 3;
  const int n0 = (idq % gridDim.x) * 128;
  const int m0 = (xcd + 8 * (idq / gridDim.x)) * 128;
  const int wr = (wv >> 1) * 64, wc = (wv & 1) * 64;
  const int mrow = ln & 15, quad = ln >> 4;
  const int srow = ln >> 2;
  const int skof = (ln & 3) * 8;
  const int kchunk = Kd / gridDim.z;
  const int kbeg = blockIdx.z * kchunk;
  const int kend = kbeg + kchunk;

  auto stage = [&](int pb, int k0) {
#pragma unroll
    for (int j = 0; j < 2; j++) {
      int row = 16 * (4 * j + wv) + srow;
      gload16(A + (size_t)(m0 + row) * lda + k0 + skof,
              (char*)&As[pb][0][0] + (size_t)(4 * j + wv) * 1024);
    }
#pragma unroll
    for (int j = 0; j < 2; j++) {
      int row = 16 * (4 * j + wv) + srow;
      size_t baddr = woff + (size_t)(n0 + row) * ldb + k0 + skof;
      if (wbf) {
        gload16((const bf16*)Wt + baddr, (char*)&Bs[pb][0][0] + (size_t)(4 * j + wv) * 1024);
      } else {
        const float* gp = (const float*)Wt + baddr;
        short8 v;
#pragma unroll
        for (int u = 0; u < 8; u++) { bf16 t = __float2bfloat16(gp[u]); v[u] = *(short*)&t; }
        *(short8*)&Bs[pb][row][skof] = v;
      }
    }
  };

  f32x4 acc[4][4];
#pragma unroll
  for (int i = 0; i < 4; i++)
#pragma unroll
    for (int j = 0; j < 4; j++) acc[i][j] = (f32x4){0.f, 0.f, 0.f, 0.f};

  stage(0, kbeg);
  int p = 0;
  for (int k0 = kbeg; k0 < kend; k0 += 32) {
    __syncthreads();                       // drains prefetch into buf p (vmcnt before barrier)
    if (k0 + 32 < kend) stage(p ^ 1, k0 + 32);   // in flight during compute
    short8 af[4], bfr[4];
#pragma unroll
    for (int t = 0; t < 4; t++) {
      af[t]  = *(const short8*)&As[p][wr + t * 16 + mrow][quad * 8];
      bfr[t] = *(const short8*)&Bs[p][wc + t * 16 + mrow][quad * 8];
    }
#pragma unroll
    for (int i = 0; i < 4; i++)
#pragma unroll
      for (int j = 0; j < 4; j++)
        acc[i][j] = __builtin_amdgcn_mfma_f32_16x16x32_bf16(af[i], bfr[j], acc[i][j], 0, 0, 0);
    p ^= 1;
  }

  bf16* slice = (MODE == 0) ? (bf16*)C_ + (size_t)blockIdx.z * T_ * D_ : (bf16*)C_;
#pragma unroll
  for (int tj = 0; tj < 4; tj++) {
    int n = n0 + wc + tj * 16 + mrow;
    float bv = (MODE == 3) ? ldin(bias, boff + n, wbf) : 0.f;
#pragma unroll
    for (int ti = 0; ti < 4; ti++) {
      int mbase = m0 + wr + ti * 16 + quad * 4;
#pragma unroll
      for (int r = 0; r < 4; r++) {
        int m = mbase + r;
        float v = acc[ti][tj][r];
        slice[(size_t)m * ldc + n] = __float2bfloat16(MODE == 3 ? v + bv : v);
      }
    }
  }
}

// ---------------- MFMA flash attention: 128-query tile, swizzled V transpose --------
__global__ __launch_bounds__(256) void attn_kernel(const bf16* __restrict__ qkv,
                                                   bf16* __restrict__ o) {
  __shared__ bf16 Qs[128][72];
  __shared__ bf16 Ks[64][72];
  __shared__ bf16 Vt[64][72];    // [d][k ^ swz(d)]
  __shared__ bf16 Ps[128][72];   // [q][k]
  const int tid = threadIdx.x;
  const int ln = tid & 63, wv = tid >> 6;
  const int mrow = ln & 15, quad = ln >> 4;
  const int qt = blockIdx.x & 7, hh = (blockIdx.x >> 3) & 7, b = blockIdx.x >> 6;
  const int q0 = qt * 128;
  const int sr = tid >> 2;
  const int sg = tid & 3;
  const int sc = sg * 8;

#pragma unroll
  for (int p = 0; p < 2; p++) {
    int row = sr + p * 64;
    const bf16* src = qkv + (size_t)(b * S_ + q0 + row) * D3_ + hh * 64;
    *(short8*)&Qs[row][sc]      = *(const short8*)(src + sc);
    *(short8*)&Qs[row][sc + 32] = *(const short8*)(src + sc + 32);
  }
  __syncthreads();
  short8 aq[2][2];
#pragma unroll
  for (int g = 0; g < 2; g++) {
    aq[g][0] = *(const short8*)&Qs[wv * 32 + g * 16 + mrow][quad * 8];
    aq[g][1] = *(const short8*)&Qs[wv * 32 + g * 16 + mrow][quad * 8 + 32];
  }

  float m_st[2][4], l_st[2][4];
  f32x4 oacc[2][4];
#pragma unroll
  for (int g = 0; g < 2; g++)
#pragma unroll
    for (int t = 0; t < 4; t++) {
      m_st[g][t] = -1e30f; l_st[g][t] = 0.f;
      oacc[g][t] = (f32x4){0.f, 0.f, 0.f, 0.f};
    }

  for (int kt = 0; kt < 16; kt++) {
    int k0 = kt * 64;
    __syncthreads();
    {
      const bf16* src = qkv + (size_t)(b * S_ + k0 + sr) * D3_ + D_ + hh * 64;
      *(short8*)&Ks[sr][sc]      = *(const short8*)(src + sc);
      *(short8*)&Ks[sr][sc + 32] = *(const short8*)(src + sc + 32);
    }
    {
      const bf16* src = qkv + (size_t)(b * S_ + k0 + sr) * D3_ + 2 * D_ + hh * 64;
      short8 v0 = *(const short8*)(src + sc);
      short8 v1 = *(const short8*)(src + sc + 32);
      int col0 = sr ^ (sg << 4);
      int col1 = sr ^ (((sg + 4) & 3) << 4);
#pragma unroll
      for (int u = 0; u < 8; u++) {
        *(short*)&Vt[sc + u][col0]      = v0[u];
        *(short*)&Vt[sc + 32 + u][col1] = v1[u];
      }
    }
    __syncthreads();
    f32x4 s[2][4];
#pragma unroll
    for (int g = 0; g < 2; g++)
#pragma unroll
      for (int t = 0; t < 4; t++) {
        s[g][t] = (f32x4){0.f, 0.f, 0.f, 0.f};
#pragma unroll
        for (int ks = 0; ks < 2; ks++) {
          short8 bk = *(const short8*)&Ks[t * 16 + mrow][quad * 8 + ks * 32];
          s[g][t] = __builtin_amdgcn_mfma_f32_16x16x32_bf16(aq[g][ks], bk, s[g][t], 0, 0, 0);
        }
      }
#pragma unroll
    for (int g = 0; g < 2; g++)
#pragma unroll
      for (int r = 0; r < 4; r++) {
        float rm = fmaxf(fmaxf(s[g][0][r], s[g][1][r]), fmaxf(s[g][2][r], s[g][3][r])) * 0.125f;
#pragma unroll
        for (int off = 8; off; off >>= 1) rm = fmaxf(rm, __shfl_xor(rm, off, 64));
        float mnew = fmaxf(m_st[g][r], rm);
        float alpha = __expf(m_st[g][r] - mnew);
        m_st[g][r] = mnew;
        float rs = 0.f;
#pragma unroll
        for (int t = 0; t < 4; t++) {
          float p = __expf(s[g][t][r] * 0.125f - mnew);
          rs += p;
          Ps[wv * 32 + g * 16 + quad * 4 + r][t * 16 + mrow] = __float2bfloat16(p);
        }
#pragma unroll
        for (int off = 8; off; off >>= 1) rs += __shfl_xor(rs, off, 64);
        l_st[g][r] = l_st[g][r] * alpha + rs;
#pragma unroll
        for (int t = 0; t < 4; t++) oacc[g][t][r] *= alpha;
      }
#pragma unroll
    for (int g = 0; g < 2; g++) {
      short8 ap[2];
      ap[0] = *(const short8*)&Ps[wv * 32 + g * 16 + mrow][quad * 8];
      ap[1] = *(const short8*)&Ps[wv * 32 + g * 16 + mrow][quad * 8 + 32];
#pragma unroll
      for (int t = 0; t < 4; t++) {
        int d = t * 16 + mrow;
        int swz = ((d >> 3) & 3) << 4;
#pragma unroll
        for (int ks = 0; ks < 2; ks++) {
          short8 bv = *(const short8*)&Vt[d][(quad * 8 + ks * 32) ^ swz];
          oacc[g][t] = __builtin_amdgcn_mfma_f32_16x16x32_bf16(ap[ks], bv, oacc[g][t], 0, 0, 0);
        }
      }
    }
  }
#pragma unroll
  for (int g = 0; g < 2; g++)
#pragma unroll
    for (int r = 0; r < 4; r++) {
      float inv = 1.f / l_st[g][r];
      size_t base = (size_t)(b * S_ + q0 + wv * 32 + g * 16 + quad * 4 + r) * D_ + hh * 64;
#pragma unroll
      for (int t = 0; t < 4; t++)
        o[base + t * 16 + mrow] = __float2bfloat16(oacc[g][t][r] * inv);
    }
}

// ---------------- fused: sum partial slices + bias + residual + LayerNorm ----------
__global__ __launch_bounds__(256) void reduce_ln_kernel(float* __restrict__ h,
                                                        bf16* __restrict__ hb16,
                                                        const bf16* __restrict__ ps,
                                                        int nsl, int mode,
                                                        const void* __restrict__ bias,
                                                        size_t boff,
                                                        const float* __restrict__ cw,
                                                        const void* __restrict__ eb2p,
                                                        size_t e2off,
                                                        const void* __restrict__ g,
                                                        const void* __restrict__ beta,
                                                        size_t off,
                                                        const int* __restrict__ flag) {
  const int bf = flag[0];
  int t = blockIdx.x, tid = threadIdx.x;
  __shared__ float r1[256], r2[256];
  const size_t base = (size_t)t * D_;
  float o0 = 0.f, o1 = 0.f;
  for (int s = 0; s < nsl; s++) {
    o0 += b2f(ps[(size_t)s * T_ * D_ + base + tid]);
    o1 += b2f(ps[(size_t)s * T_ * D_ + base + tid + 256]);
  }
  if (mode == 0) {
    o0 += ldin(bias, boff + tid, bf);
    o1 += ldin(bias, boff + tid + 256, bf);
  } else {
#pragma unroll
    for (int e = 0; e < 4; e++) {
      float w = cw[t * 4 + e];
      o0 += w * ldin(eb2p, e2off + e * D_ + tid, bf);
      o1 += w * ldin(eb2p, e2off + e * D_ + tid + 256, bf);
    }
  }
  float* hr = h + base;
  float v0 = hr[tid] + o0;
  float v1 = hr[tid + 256] + o1;
  r1[tid] = v0 + v1;
  r2[tid] = v0 * v0 + v1 * v1;
  __syncthreads();
  for (int w = 128; w; w >>= 1) { if (tid < w) { r1[tid] += r1[tid + w]; r2[tid] += r2[tid + w]; } __syncthreads(); }
  float mean = r1[0] * (1.f / D_);
  float var  = r2[0] * (1.f / D_) - mean * mean;
  float rstd = rsqrtf(var + 1e-5f);
  float n0 = (v0 - mean) * rstd * ldin(g, off + tid, bf) + ldin(beta, off + tid, bf);
  float n1 = (v1 - mean) * rstd * ldin(g, off + tid + 256, bf) + ldin(beta, off + tid + 256, bf);
  hr[tid] = n0;
  hr[tid + 256] = n1;
  hb16[base + tid] = __float2bfloat16(n0);
  hb16[base + tid + 256] = __float2bfloat16(n1);
}

// ---------------- MoE gating: softmax over E=4, top-2; emits routing info ----------
__global__ __launch_bounds__(256) void gate_kernel(const float* __restrict__ hbuf,
                                                   const void* __restrict__ gw, size_t gwoff,
                                                   const void* __restrict__ gb, size_t gboff,
                                                   float* __restrict__ cw,
                                                   int* __restrict__ einfo,
                                                   float* __restrict__ w0a,
                                                   float* __restrict__ w1a,
                                                   const int* __restrict__ flag) {
  const int bf = flag[0];
  int lane = threadIdx.x & 63, wv = threadIdx.x >> 6;
  int t = blockIdx.x * 4 + wv;
  const float* xr = hbuf + (size_t)t * D_;
  float a[4] = {0, 0, 0, 0};
  for (int d = lane; d < D_; d += 64) {
    float xv = xr[d];
#pragma unroll
    for (int e = 0; e < 4; e++) a[e] += xv * ldin(gw, gwoff + e * D_ + d, bf);
  }
#pragma unroll
  for (int e = 0; e < 4; e++)
    for (int off = 32; off; off >>= 1) a[e] += __shfl_xor(a[e], off, 64);
  if (lane == 0) {
    float lg[4];
#pragma unroll
    for (int e = 0; e < 4; e++) lg[e] = a[e] + ldin(gb, gboff + e, bf);
    float m = fmaxf(fmaxf(lg[0], lg[1]), fmaxf(lg[2], lg[3]));
    float p[4], s = 0.f;
#pragma unroll
    for (int e = 0; e < 4; e++) { p[e] = __expf(lg[e] - m); s += p[e]; }
#pragma unroll
    for (int e = 0; e < 4; e++) p[e] /= s;
    int i0 = 0;
    for (int e = 1; e < 4; e++) if (p[e] > p[i0]) i0 = e;
    int i1 = -1;
    for (int e = 0; e < 4; e++) if (e != i0 && (i1 < 0 || p[e] > p[i1])) i1 = e;
    float s2 = p[i0] + p[i1];
    float ww0 = p[i0] / s2, ww1 = p[i1] / s2;
    float outw[4] = {0, 0, 0, 0};
    outw[i0] = ww0; outw[i1] = ww1;
#pragma unroll
    for (int e = 0; e < 4; e++) cw[t * 4 + e] = outw[e];
    einfo[t] = i0 | (i1 << 4);
    w0a[t] = ww0; w1a[t] = ww1;
  }
}

// ---------------- route scan: counts -> offsets + tile table (1 block) ----------------
__global__ __launch_bounds__(256) void route_scan_kernel(const int* __restrict__ einfo,
                                                         int* __restrict__ off,
                                                         int* __restrict__ endp,
                                                         int* __restrict__ cur,
                                                         int* __restrict__ tmap) {
  __shared__ int red[4][256];
  int tid = threadIdx.x;
  int c[4] = {0, 0, 0, 0};
  for (int t = tid; t < T_; t += 256) {
    int inf = einfo[t];
    c[inf & 15]++;
    c[(inf >> 4) & 15]++;
  }
#pragma unroll
  for (int e = 0; e < 4; e++) red[e][tid] = c[e];
  __syncthreads();
  for (int w = 128; w; w >>= 1) {
    if (tid < w)
#pragma unroll
      for (int e = 0; e < 4; e++) red[e][tid] += red[e][tid + w];
    __syncthreads();
  }
  if (tid == 0) {
    int o = 0, idx = 0;
#pragma unroll
    for (int e = 0; e < 4; e++) {
      int cnt = red[e][0];
      off[e] = o;
      endp[e] = o + cnt;
      cur[e] = 0;
      int nt = (cnt + 127) >> 7;
      for (int i = 0; i < nt; i++) tmap[1 + idx++] = e | (i << 8);
      o += nt << 7;
    }
    tmap[0] = idx;   // total active m-tiles (<= 131)
  }
}

// ---------------- scatter: token -> (expert bucket, rank), ballot-aggregated --------
__global__ __launch_bounds__(256) void scatter_kernel(const int* __restrict__ einfo,
                                                      const float* __restrict__ w0a,
                                                      const float* __restrict__ w1a,
                                                      const int* __restrict__ off,
                                                      int* __restrict__ cur,
                                                      int* __restrict__ pack,
                                                      float* __restrict__ wlist) {
  int t = blockIdx.x * 256 + threadIdx.x;
  int lane = threadIdx.x & 63;
  int inf = einfo[t];
#pragma unroll
  for (int rank = 0; rank < 2; rank++) {
    int my_e = (rank == 0) ? (inf & 15) : ((inf >> 4) & 15);
    float w = (rank == 0) ? w0a[t] : w1a[t];
#pragma unroll
    for (int e = 0; e < 4; e++) {
      bool p = (my_e == e);
      unsigned long long mask = __ballot(p);
      if (!mask) continue;
      int leader = __ffsll((long long)mask) - 1;
      int base = 0;
      if (lane == leader) base = atomicAdd(&cur[e], (int)__popcll(mask));
      base = __shfl(base, leader, 64);
      if (p) {
        int pos = off[e] + base + (int)__popcll(mask & ((1ULL << lane) - 1ULL));
        pack[pos] = t * 2 + rank;
        wlist[pos] = w;
      }
    }
  }
}

// ---------------- sparse MoE mat1 (BK=32, dbuf, tile-table, XCD-swizzled) ------------
__global__ __launch_bounds__(256) void moe_mat1_kernel(
    const bf16* __restrict__ A, const void* __restrict__ Wt, size_t woff,
    const void* __restrict__ bias, size_t boff, bf16* __restrict__ hid,
    const int* __restrict__ off, const int* __restrict__ endp,
    const int* __restrict__ pack, const float* __restrict__ wlist,
    const int* __restrict__ tmap, const int* __restrict__ flag) {
  const int wbf = flag[0];
  int id = blockIdx.x + 8 * blockIdx.y;
  int xcd = id & 7, idq = id >> 3;
  int wx = idq & 7, wy = xcd + 8 * (idq >> 3);
  if (wy >= tmap[0]) return;
  int ent = tmap[1 + wy];
  const int e = ent & 255, mt = ent >> 8;
  const int o = off[e], en = endp[e];
  const int n0 = wx * 128;
  __shared__ bf16 As[2][128][32];
  __shared__ bf16 Bs[2][128][32];
  const int tid = threadIdx.x;
  const int ln = tid & 63, wv = tid >> 6;
  const int m0 = o + mt * 128;
  const int wr = (wv >> 1) * 64, wc = (wv & 1) * 64;
  const int mrow = ln & 15, quad = ln >> 4;
  const int srow = ln >> 2;
  const int skof = (ln & 3) * 8;
  int tokr[2];
#pragma unroll
  for (int j = 0; j < 2; j++) {
    int pos = m0 + 16 * (4 * j + wv) + srow;
    tokr[j] = pack[min(pos, en - 1)] >> 1;
  }
  const size_t wbase = woff + (size_t)e * 1024 * 512;

  auto stage = [&](int pb, int k0) {
#pragma unroll
    for (int j = 0; j < 2; j++)
      gload16(A + (size_t)tokr[j] * 512 + k0 + skof,
              (char*)&As[pb][0][0] + (size_t)(4 * j + wv) * 1024);
#pragma unroll
    for (int j = 0; j < 2; j++) {
      int row = 16 * (4 * j + wv) + srow;
      size_t baddr = wbase + (size_t)(n0 + row) * 512 + k0 + skof;
      if (wbf) {
        gload16((const bf16*)Wt + baddr, (char*)&Bs[pb][0][0] + (size_t)(4 * j + wv) * 1024);
      } else {
        const float* gp = (const float*)Wt + baddr;
        short8 v;
#pragma unroll
        for (int u = 0; u < 8; u++) { bf16 t = __float2bfloat16(gp[u]); v[u] = *(short*)&t; }
        *(short8*)&Bs[pb][row][skof] = v;
      }
    }
  };

  f32x4 acc[4][4];
#pragma unroll
  for (int i = 0; i < 4; i++)
#pragma unroll
    for (int j = 0; j < 4; j++) acc[i][j] = (f32x4){0.f, 0.f, 0.f, 0.f};

  stage(0, 0);
  int p = 0;
  for (int k0 = 0; k0 < 512; k0 += 32) {
    __syncthreads();
    if (k0 + 32 < 512) stage(p ^ 1, k0 + 32);
    short8 af[4], bfr[4];
#pragma unroll
    for (int t = 0; t < 4; t++) {
      af[t]  = *(const short8*)&As[p][wr + t * 16 + mrow][quad * 8];
      bfr[t] = *(const short8*)&Bs[p][wc + t * 16 + mrow][quad * 8];
    }
#pragma unroll
    for (int i = 0; i < 4; i++)
#pragma unroll
      for (int j = 0; j < 4; j++)
        acc[i][j] = __builtin_amdgcn_mfma_f32_16x16x32_bf16(af[i], bfr[j], acc[i][j], 0, 0, 0);
    p ^= 1;
  }

#pragma unroll
  for (int ti = 0; ti < 4; ti++) {
#pragma unroll
    for (int r = 0; r < 4; r++) {
      int pos = m0 + wr + ti * 16 + quad * 4 + r;
      float w = (pos < en) ? wlist[pos] : 0.f;
#pragma unroll
      for (int tj = 0; tj < 4; tj++) {
        int ncol = n0 + wc + tj * 16 + mrow;
        float v = acc[ti][tj][r] + ldin(bias, boff + e * 1024 + ncol, wbf);
        hid[(size_t)pos * 1024 + ncol] = __float2bfloat16(fmaxf(v, 0.f) * w);
      }
    }
  }
}

// ---------------- sparse MoE mat2 (BK=32, dbuf, tile-table, XCD-swizzled, z=2) -------
__global__ __launch_bounds__(256) void moe_mat2_kernel(
    const bf16* __restrict__ hid, const void* __restrict__ Wt, size_t woff,
    bf16* __restrict__ psl,
    const int* __restrict__ off, const int* __restrict__ endp,
    const int* __restrict__ pack, const int* __restrict__ tmap,
    const int* __restrict__ flag) {
  const int wbf = flag[0];
  int id = blockIdx.x + 4 * blockIdx.y;
  int xcd = id & 7, idq = id >> 3;
  int wx = idq & 3, wy = xcd + 8 * (idq >> 2);
  if (wy >= tmap[0]) return;
  int ent = tmap[1 + wy];
  const int e = ent & 255, mt = ent >> 8;
  const int o = off[e], en = endp[e];
  const int n0 = wx * 128;
  __shared__ bf16 As[2][128][32];
  __shared__ bf16 Bs[2][128][32];
  const int tid = threadIdx.x;
  const int ln = tid & 63, wv = tid >> 6;
  const int m0 = o + mt * 128;
  const int wr = (wv >> 1) * 64, wc = (wv & 1) * 64;
  const int mrow = ln & 15, quad = ln >> 4;
  const int srow = ln >> 2;
  const int skof = (ln & 3) * 8;
  const int kbeg = blockIdx.z * 512;
  const size_t wbase = woff + (size_t)e * 512 * 1024;

  auto stage = [&](int pb, int k0) {
#pragma unroll
    for (int j = 0; j < 2; j++) {
      int row = 16 * (4 * j + wv) + srow;
      gload16(hid + (size_t)(m0 + row) * 1024 + k0 + skof,
              (char*)&As[pb][0][0] + (size_t)(4 * j + wv) * 1024);
    }
#pragma unroll
    for (int j = 0; j < 2; j++) {
      int row = 16 * (4 * j + wv) + srow;
      size_t baddr = wbase + (size_t)(n0 + row) * 1024 + k0 + skof;
      if (wbf) {
        gload16((const bf16*)Wt + baddr, (char*)&Bs[pb][0][0] + (size_t)(4 * j + wv) * 1024);
      } else {
        const float* gp = (const float*)Wt + baddr;
        short8 v;
#pragma unroll
        for (int u = 0; u < 8; u++) { bf16 t = __float2bfloat16(gp[u]); v[u] = *(short*)&t; }
        *(short8*)&Bs[pb][row][skof] = v;
      }
    }
  };

  f32x4 acc[4][4];
#pragma unroll
  for (int i = 0; i < 4; i++)
#pragma unroll
    for (int j = 0; j < 4; j++) acc[i][j] = (f32x4){0.f, 0.f, 0.f, 0.f};

  stage(0, kbeg);
  int p = 0;
  for (int k0 = kbeg; k0 < kbeg + 512; k0 += 32) {
    __syncthreads();
    if (k0 + 32 < kbeg + 512) stage(p ^ 1, k0 + 32);
    short8 af[4], bfr[4];
#pragma unroll
    for (int t = 0; t < 4; t++) {
      af[t]  = *(const short8*)&As[p][wr + t * 16 + mrow][quad * 8];
      bfr[t] = *(const short8*)&Bs[p][wc + t * 16 + mrow][quad * 8];
    }
#pragma unroll
    for (int i = 0; i < 4; i++)
#pragma unroll
      for (int j = 0; j < 4; j++)
        acc[i][j] = __builtin_amdgcn_mfma_f32_16x16x32_bf16(af[i], bfr[j], acc[i][j], 0, 0, 0);
    p ^= 1;
  }

#pragma unroll
  for (int ti = 0; ti < 4; ti++) {
#pragma unroll
    for (int r = 0; r < 4; r++) {
      int pos = m0 + wr + ti * 16 + quad * 4 + r;
      if (pos < en) {
        int pk = pack[pos];
        int tok = pk >> 1, rank = pk & 1;
        bf16* dst = psl + (size_t)(rank * 2 + blockIdx.z) * T_ * D_ + (size_t)tok * D_;
#pragma unroll
        for (int tj = 0; tj < 4; tj++) {
          int ncol = n0 + wc + tj * 16 + mrow;
          dst[ncol] = __float2bfloat16(acc[ti][tj][r]);
        }
      }
    }
  }
}

// ---------------- head ----------------
__global__ __launch_bounds__(256) void head_kernel(const float* __restrict__ hbuf,
                                                   const void* __restrict__ hw,
                                                   const void* __restrict__ hb,
                                                   void* __restrict__ out,
                                                   const int* __restrict__ flag) {
  const int bf = flag[0];
  int bq = blockIdx.x, tid = threadIdx.x;
  int b = bq / 3, q = bq % 3;
  __shared__ float red[256];
  const float* xr = hbuf + (size_t)(b * S_ + (S_ - 1)) * D_;
  float sacc = xr[tid] * ldin(hw, (size_t)q * D_ + tid, bf)
             + xr[tid + 256] * ldin(hw, (size_t)q * D_ + tid + 256, bf);
  red[tid] = sacc; __syncthreads();
  for (int w = 128; w; w >>= 1) { if (tid < w) red[tid] += red[tid + w]; __syncthreads(); }
  if (tid == 0) {
    float r = red[0] + ldin(hb, q, bf);
    if (bf) ((bf16*)out)[bq] = __float2bfloat16(r);
    else    ((float*)out)[bq] = r;
  }
}

extern "C" void kernel_launch(void* const* d_in, const int* in_sizes, int n_in,
                              void* d_out, int out_size, void* d_ws, size_t ws_size,
                              hipStream_t stream) {
  const void* x    = d_in[0];
  const void* Wp   = d_in[1];
  const void* bp   = d_in[2];
  const void* femb = d_in[3];
  const void* qkvw = d_in[4];
  const void* qkvb = d_in[5];
  const void* ow   = d_in[6];
  const void* ob   = d_in[7];
  const void* g1   = d_in[8];
  const void* be1  = d_in[9];
  const void* gw   = d_in[10];
  const void* gb   = d_in[11];
  const void* ew1  = d_in[12];
  const void* eb1  = d_in[13];
  const void* ew2  = d_in[14];
  const void* eb2  = d_in[15];
  const void* g2   = d_in[16];
  const void* be2  = d_in[17];
  const void* hw   = d_in[18];
  const void* hb   = d_in[19];
  const int*  freq = (const int*)d_in[20];

  // workspace layout: ~90 MB peak (proven-safe bound: 101 MB)
  int*   flag  = (int*)d_ws;                        // 64 ints
  int*   off   = flag + 64;                         // 4
  int*   endp  = off + 4;                           // 4
  int*   cur   = endp + 4;                          // 4 (+pad)
  int*   einfo = flag + 128;                        // T ints
  float* w0a   = (float*)(einfo + T_);              // T
  float* w1a   = w0a + T_;                          // T
  int*   pack  = (int*)(w1a + T_);                  // CAP ints
  float* wlist = (float*)(pack + CAP_);             // CAP
  int*   tmap  = (int*)(wlist + CAP_);              // 160 ints (count + tiles)
  float* xn    = (float*)(tmap + 160);              // 65536
  float* h     = xn + 65536;                        // T*D f    (16 MB)
  float* cw    = h + (size_t)T_ * D_;               // T*4
  bf16*  hb16  = (bf16*)(cw + (size_t)T_ * E_);     // T*D bf16 (8 MB)
  bf16*  R     = hb16 + (size_t)T_ * D_;            // alias region
  bf16*  qkvb16 = R;                                // T*3D bf16 (24 MB)
  bf16*  ao    = R + (size_t)T_ * D3_;              // T*D bf16  (8 MB)
  bf16*  hid   = R;                                 // CAP*1024 bf16 (~33 MB)
  bf16*  psl   = R + (size_t)CAP_ * 1024;           // 4x T*D bf16 (32 MB partial slices)

  detect_kernel<<<1, 64, 0, stream>>>(x, flag);
  instnorm_kernel<<<B_ * F_, 256, 0, stream>>>(x, xn, flag);
  input_proj_kernel<<<(T_ * D_) / 256, 256, 0, stream>>>(xn, Wp, bp, femb, freq, h, hb16, flag);

  for (int l = 0; l < 3; l++) {
    // QKV projection -> bf16
    mfma_gemm<3><<<dim3(D3_ / 128, T_ / 128), 256, 0, stream>>>(
        hb16, qkvw, (size_t)l * D3_ * D_, qkvb, (size_t)l * D3_, qkvb16,
        D_, D_, D_, D3_, flag);
    attn_kernel<<<B_ * H_ * (S_ / 128), 256, 0, stream>>>(qkvb16, ao);
    // O-projection: split-K=2 -> slices 0,1; fused reduce + bias + LN
    mfma_gemm<0><<<dim3(D_ / 128, T_ / 128, 2), 256, 0, stream>>>(
        ao, ow, (size_t)l * D_ * D_, nullptr, 0, psl,
        D_, D_, D_, D_, flag);
    reduce_ln_kernel<<<T_, 256, 0, stream>>>(
        h, hb16, psl, 2, 0, ob, (size_t)l * D_, nullptr, nullptr, 0,
        g1, be1, (size_t)l * D_, flag);
    // gating + routing
    gate_kernel<<<T_ / 4, 256, 0, stream>>>(h, gw, (size_t)l * E_ * D_, gb, (size_t)l * E_,
                                            cw, einfo, w0a, w1a, flag);
    route_scan_kernel<<<1, 256, 0, stream>>>(einfo, off, endp, cur, tmap);
    scatter_kernel<<<T_ / 256, 256, 0, stream>>>(einfo, w0a, w1a, off, cur, pack, wlist);
    // sparse expert GEMMs (hid aliases qkv+ao, both dead here)
    moe_mat1_kernel<<<dim3(8, 136), 256, 0, stream>>>(
        hb16, ew1, (size_t)l * E_ * 1024 * 512, eb1, (size_t)l * E_ * 1024, hid,
        off, endp, pack, wlist, tmap, flag);
    moe_mat2_kernel<<<dim3(4, 136, 2), 256, 0, stream>>>(
        hid, ew2, (size_t)l * E_ * 512 * 1024, psl, off, endp, pack, tmap, flag);
    reduce_ln_kernel<<<T_, 256, 0, stream>>>(
        h, hb16, psl, 4, 1, nullptr, 0, cw, eb2, (size_t)l * E_ * D_,
        g2, be2, (size_t)l * D_, flag);
  }

  head_kernel<<<24, 256, 0, stream>>>(h, hw, hb, d_out, flag);
}